// Round 12
// baseline (131.371 us; speedup 1.0000x reference)
//
#include <hip/hip_runtime.h>
#include <math.h>

#define BB 256
#define NN 1000
#define DD 128
#define HH 8
#define CC 8            // chunks per batch element
#define RC 125          // rows per chunk
#define NEG -1e9f
#define CMS 132         // cm row stride (conflict-free: (4h+nl)%32 distinct)

__device__ __forceinline__ float bf2f(unsigned int u) {
    return __uint_as_float(u << 16);
}
__device__ __forceinline__ unsigned short f2bf(float f) {
    unsigned int u = __float_as_uint(f);
    u += 0x7FFFu + ((u >> 16) & 1u);          // RNE
    return (unsigned short)(u >> 16);
}
__device__ __forceinline__ bool get_mask(const void* m, int flag, size_t idx) {
    if (flag == 1) return ((const int*)m)[idx] != 0;
    if (flag == 2) return ((const float*)m)[idx] != 0.0f;
    return ((const unsigned char*)m)[idx] != 0;
}

// ===========================================================================
// K1: stream X fp32 once: mean partials + bf16 downconvert to workspace.
// grid BB*CC = 2048 blocks (8/CU), 256 thr. Block 0 detects mask dtype.
// ===========================================================================
__global__ __launch_bounds__(256, 8) void k_stage(
        const float* __restrict__ X, float* __restrict__ partial,
        unsigned short* __restrict__ Xb,
        const unsigned int* __restrict__ maskw, int* __restrict__ flag) {
    int bid = blockIdx.x, tid = threadIdx.x;
    int b = bid >> 3, ch = bid & 7;
    if (bid == 0 && tid < 64) {
        unsigned int a0 = maskw[tid], a1 = maskw[tid + 64],
                     a2 = maskw[tid + 128], a3 = maskw[tid + 192];
        int ii = (a0 <= 1u) && (a1 <= 1u) && (a2 <= 1u) && (a3 <= 1u);
        int ff = (a0 == 0u || a0 == 0x3F800000u) && (a1 == 0u || a1 == 0x3F800000u) &&
                 (a2 == 0u || a2 == 0x3F800000u) && (a3 == 0u || a3 == 0x3F800000u);
        int ai = __all(ii), af = __all(ff);
        if (tid == 0) *flag = ai ? 1 : (af ? 2 : 0);
    }
    int c = tid & 31, s = tid >> 5;                 // float4 col, row stripe
    const float4* Xr = (const float4*)(X + (size_t)b * NN * DD);
    uint2* Xw = (uint2*)Xb;
    float4 acc = make_float4(0.f, 0.f, 0.f, 0.f);
    int n0 = ch * RC;
    for (int nl = s; nl < RC; nl += 8) {
        int n = n0 + nl;
        float4 v = Xr[n * 32 + c];
        acc.x += v.x; acc.y += v.y; acc.z += v.z; acc.w += v.w;
        uint2 p;
        p.x = (unsigned)f2bf(v.x) | ((unsigned)f2bf(v.y) << 16);
        p.y = (unsigned)f2bf(v.z) | ((unsigned)f2bf(v.w) << 16);
        Xw[((size_t)b * NN + n) * 32 + c] = p;
    }
    __shared__ float4 red[8][32];
    red[s][c] = acc;
    __syncthreads();
    for (int st = 4; st >= 1; st >>= 1) {
        if (s < st) {
            float4 o = red[s + st][c];
            red[s][c].x += o.x; red[s][c].y += o.y;
            red[s][c].z += o.z; red[s][c].w += o.w;
        }
        __syncthreads();
    }
    if (s == 0) {
        float4 r = red[0][c];
        float* outp = partial + ((size_t)b * CC + ch) * DD + 4 * c;
        outp[0] = r.x; outp[1] = r.y; outp[2] = r.z; outp[3] = r.w;
    }
}

// ===========================================================================
// K2: per-b query + qk vectors. grid BB, 256 thr. (proven in round 11)
// ===========================================================================
__global__ __launch_bounds__(256) void k_qk(
        const float* __restrict__ X, const float* __restrict__ Wfix,
        const float* __restrict__ Wstep, const float* __restrict__ Wnode,
        const float* __restrict__ partial, const int* __restrict__ prev,
        const int* __restrict__ first, float* __restrict__ qkg) {
    int b = blockIdx.x, tid = threadIdx.x;
    const size_t xoff = (size_t)b * NN * DD;
    __shared__ float ge[DD], sc[2 * DD], qv[DD], qp[2][DD];
    if (tid < DD) {
        float g = 0.f;
        #pragma unroll
        for (int ch = 0; ch < CC; ++ch) g += partial[((size_t)b * CC + ch) * DD + tid];
        ge[tid] = g * (1.0f / NN);
    }
    {
        int src = (tid < DD) ? first[b] : prev[b];
        sc[tid] = X[xoff + (size_t)src * DD + (tid & 127)];
    }
    __syncthreads();
    int p = tid >> 7, d = tid & 127;
    {
        float a = 0.f;
        #pragma unroll 4
        for (int k = p * 64; k < p * 64 + 64; ++k)      a += ge[k] * Wfix[(size_t)k * DD + d];
        #pragma unroll 4
        for (int k = p * 128; k < p * 128 + 128; ++k)   a += sc[k] * Wstep[(size_t)k * DD + d];
        qp[p][d] = a;
    }
    __syncthreads();
    if (tid < DD) qv[tid] = qp[0][tid] + qp[1][tid];
    __syncthreads();
    {
        const float* wrow = Wnode + (size_t)d * 384;
        #pragma unroll
        for (int h = p * 4; h < p * 4 + 4; ++h) {
            const float4* wr = (const float4*)(wrow + h * 16);
            float a = 0.f;
            #pragma unroll
            for (int j4 = 0; j4 < 4; ++j4) {
                float4 w = wr[j4];
                a += w.x * qv[h * 16 + 4 * j4]     + w.y * qv[h * 16 + 4 * j4 + 1]
                   + w.z * qv[h * 16 + 4 * j4 + 2] + w.w * qv[h * 16 + 4 * j4 + 3];
            }
            qkg[((size_t)b * HH + h) * DD + d] = 0.25f * a;   // 1/sqrt(16)
        }
    }
}

// ===========================================================================
// K3: flash chunk on bf16 X: compat -> local masked softmax -> partial PV.
// grid BB*CC = 2048 (8/CU), 256 thr, LDS ~12.7 KB.
// ===========================================================================
__global__ __launch_bounds__(256, 8) void k_flash(
        const unsigned short* __restrict__ Xb, const float* __restrict__ qkg,
        const void* __restrict__ mask, const int* __restrict__ flag,
        float* __restrict__ mqw, float* __restrict__ sqw,
        float* __restrict__ pvp) {
    int bid = blockIdx.x, tid = threadIdx.x;
    int b = bid >> 3, ch = bid & 7;
    const int n0 = ch * RC;
    const int f = *flag;

    __shared__ float qk[HH][DD];        // 4 KB
    __shared__ float cm[HH][CMS];       // 4.2 KB, conflict-free stride
    __shared__ float mloc[HH];
    __shared__ float xp[2][HH][DD];     // 8 KB

    for (int i = tid; i < HH * DD; i += 256)
        qk[i >> 7][i & 127] = qkg[(size_t)b * HH * DD + i];
    __syncthreads();

    // ---- compat: 8 lanes per row ----
    {
        int g = tid & 7, r = tid >> 3;
        #pragma unroll
        for (int it = 0; it < 4; ++it) {
            int nl = it * 32 + r;
            if (it < 3 || nl < RC) {
                int n = n0 + nl;
                const uint4* xr = (const uint4*)(Xb + ((size_t)b * NN + n) * DD);
                uint4 c0 = xr[g], c1 = xr[g + 8];
                unsigned int wsv[8] = {c0.x, c0.y, c0.z, c0.w, c1.x, c1.y, c1.z, c1.w};
                float acc[HH] = {0.f, 0.f, 0.f, 0.f, 0.f, 0.f, 0.f, 0.f};
                #pragma unroll
                for (int i = 0; i < 8; ++i) {
                    int col = (i < 4) ? (8 * g + 2 * i) : (64 + 8 * g + 2 * (i - 4));
                    float lo = bf2f(wsv[i] & 0xffffu), hi = bf2f(wsv[i] >> 16);
                    #pragma unroll
                    for (int h = 0; h < HH; ++h)
                        acc[h] += lo * qk[h][col] + hi * qk[h][col + 1];
                }
                #pragma unroll
                for (int h = 0; h < HH; ++h) {
                    acc[h] += __shfl_xor(acc[h], 1, 8);
                    acc[h] += __shfl_xor(acc[h], 2, 8);
                    acc[h] += __shfl_xor(acc[h], 4, 8);
                }
                float val = acc[0];
                #pragma unroll
                for (int h = 1; h < HH; ++h) val = (g == h) ? acc[h] : val;
                bool mk = get_mask(mask, f, (size_t)b * NN + n);
                cm[g][nl] = mk ? NEG : val;
            }
        }
    }
    __syncthreads();

    // ---- local max per head (32 lanes/head) ----
    {
        int h = tid >> 5, l = tid & 31;
        float mx = -INFINITY;
        for (int nl = l; nl < RC; nl += 32) mx = fmaxf(mx, cm[h][nl]);
        #pragma unroll
        for (int off = 16; off >= 1; off >>= 1) mx = fmaxf(mx, __shfl_xor(mx, off, 32));
        if (l == 0) mloc[h] = mx;
    }
    __syncthreads();

    // ---- exp + local sum ----
    {
        int h = tid >> 5, l = tid & 31;
        float m_h = mloc[h];
        float sm = 0.f;
        for (int nl = l; nl < RC; nl += 32) {
            float p = __expf(cm[h][nl] - m_h);
            cm[h][nl] = p;
            sm += p;
        }
        #pragma unroll
        for (int off = 16; off >= 1; off >>= 1) sm += __shfl_xor(sm, off, 32);
        if (l == 0) {
            sqw[((size_t)b * CC + ch) * HH + h] = sm;
            mqw[((size_t)b * CC + ch) * HH + h] = m_h;
        }
    }
    __syncthreads();

    // ---- partial PV: 2 row-stripes x 128 d (bf16 scalar loads, L2-hit) ----
    {
        int s2 = tid >> 7, d = tid & 127;
        float acc[HH] = {0.f, 0.f, 0.f, 0.f, 0.f, 0.f, 0.f, 0.f};
        for (int nl = s2; nl < RC; nl += 2) {
            float x = bf2f((unsigned int)Xb[((size_t)b * NN + n0 + nl) * DD + d]);
            #pragma unroll
            for (int h = 0; h < HH; ++h) acc[h] += cm[h][nl] * x;
        }
        #pragma unroll
        for (int h = 0; h < HH; ++h) xp[s2][h][d] = acc[h];
        __syncthreads();
        if (s2 == 0) {
            #pragma unroll
            for (int h = 0; h < HH; ++h)
                pvp[(((size_t)b * CC + ch) * HH + h) * DD + d] = xp[0][h][d] + xp[1][h][d];
        }
    }
}

// ===========================================================================
// K4: per-b flash-combine -> heads -> glimpse -> gq. grid BB, 256 thr.
// ===========================================================================
__global__ __launch_bounds__(256) void k_comb(
        const float* __restrict__ Wnode, const float* __restrict__ Wout,
        const float* __restrict__ mqw, const float* __restrict__ sqw,
        const float* __restrict__ pvp, float* __restrict__ gqg) {
    int b = blockIdx.x, tid = threadIdx.x;
    __shared__ float wq[CC][HH], Sh[HH];
    __shared__ float xa[HH][DD], qp[2][DD], hd[DD], gl[DD];
    if (tid < HH) {
        float m = mqw[((size_t)b * CC) * HH + tid];
        #pragma unroll
        for (int ch = 1; ch < CC; ++ch)
            m = fmaxf(m, mqw[((size_t)b * CC + ch) * HH + tid]);
        float S = 0.f;
        #pragma unroll
        for (int ch = 0; ch < CC; ++ch) {
            float wgt = __expf(mqw[((size_t)b * CC + ch) * HH + tid] - m);
            wq[ch][tid] = wgt;
            S += sqw[((size_t)b * CC + ch) * HH + tid] * wgt;
        }
        Sh[tid] = 1.0f / S;
    }
    __syncthreads();
    for (int idx = tid; idx < HH * DD; idx += 256) {
        int h = idx >> 7, d = idx & 127;
        float a = 0.f;
        #pragma unroll
        for (int ch = 0; ch < CC; ++ch)
            a += pvp[(((size_t)b * CC + ch) * HH + h) * DD + d] * wq[ch][h];
        xa[h][d] = a * Sh[h];
    }
    __syncthreads();
    int p = tid >> 7, t = tid & 127;
    {
        int h = t >> 4;
        float a = 0.f;
        #pragma unroll 4
        for (int d = p * 64; d < p * 64 + 64; ++d)
            a += xa[h][d] * Wnode[(size_t)d * 384 + 128 + t];
        qp[p][t] = a;
    }
    __syncthreads();
    if (tid < DD) hd[tid] = qp[0][tid] + qp[1][tid];
    __syncthreads();
    {
        float a = 0.f;
        #pragma unroll 4
        for (int k = p * 64; k < p * 64 + 64; ++k) a += hd[k] * Wout[(size_t)k * DD + t];
        qp[p][t] = a;
    }
    __syncthreads();
    if (tid < DD) gl[tid] = qp[0][tid] + qp[1][tid];
    __syncthreads();
    {
        const float4* wr = (const float4*)(Wnode + (size_t)t * 384 + 256 + p * 64);
        float a = 0.f;
        #pragma unroll
        for (int j4 = 0; j4 < 16; ++j4) {
            float4 w = wr[j4];
            int k = p * 64 + 4 * j4;
            a += w.x * gl[k] + w.y * gl[k + 1] + w.z * gl[k + 2] + w.w * gl[k + 3];
        }
        qp[p][t] = a;
    }
    __syncthreads();
    if (tid < DD) gqg[(size_t)b * DD + tid] = (qp[0][tid] + qp[1][tid]) * 0.08838834764831845f;
}

// ===========================================================================
// K5: logits chunk on bf16 X: dot -> tanh clip -> mask -> exp-partial (base 10).
// grid BB*CC = 2048 (8/CU), 256 thr.
// ===========================================================================
__global__ __launch_bounds__(256, 8) void k_logits(
        const unsigned short* __restrict__ Xb, const float* __restrict__ gqg,
        const void* __restrict__ mask, const int* __restrict__ flag,
        float* __restrict__ lg, float* __restrict__ esumg) {
    int bid = blockIdx.x, tid = threadIdx.x;
    int b = bid >> 3, ch = bid & 7;
    const int n0 = ch * RC;
    const int f = *flag;
    __shared__ float gqv[DD];
    __shared__ float redw[4];
    if (tid < DD) gqv[tid] = gqg[(size_t)b * DD + tid];
    __syncthreads();
    int g = tid & 7, r = tid >> 3;
    float esum = 0.f;
    #pragma unroll
    for (int it = 0; it < 4; ++it) {
        int nl = it * 32 + r;
        if (it < 3 || nl < RC) {
            int n = n0 + nl;
            const uint4* xr = (const uint4*)(Xb + ((size_t)b * NN + n) * DD);
            uint4 c0 = xr[g], c1 = xr[g + 8];
            unsigned int wsv[8] = {c0.x, c0.y, c0.z, c0.w, c1.x, c1.y, c1.z, c1.w};
            float a = 0.f;
            #pragma unroll
            for (int i = 0; i < 8; ++i) {
                int col = (i < 4) ? (8 * g + 2 * i) : (64 + 8 * g + 2 * (i - 4));
                a += bf2f(wsv[i] & 0xffffu) * gqv[col] + bf2f(wsv[i] >> 16) * gqv[col + 1];
            }
            a += __shfl_xor(a, 1, 8);
            a += __shfl_xor(a, 2, 8);
            a += __shfl_xor(a, 4, 8);
            if (g == 0) {
                float l = 10.0f * tanhf(a);
                if (get_mask(mask, f, (size_t)b * NN + n)) l = NEG;
                lg[(size_t)b * NN + n] = l;
                esum += __expf(l - 10.0f);          // logits <= 10 always
            }
        }
    }
    #pragma unroll
    for (int off = 32; off >= 1; off >>= 1) esum += __shfl_xor(esum, off, 64);
    if ((tid & 63) == 0) redw[tid >> 6] = esum;
    __syncthreads();
    if (tid == 0) esumg[(size_t)b * CC + ch] = redw[0] + redw[1] + redw[2] + redw[3];
}

// ===========================================================================
// K6: lse + store. grid BB, 256 thr.
// ===========================================================================
__global__ __launch_bounds__(256) void k_final(
        const float* __restrict__ lg, const float* __restrict__ esumg,
        float* __restrict__ out) {
    int b = blockIdx.x, tid = threadIdx.x;
    float s = 0.f;
    #pragma unroll
    for (int ch = 0; ch < CC; ++ch) s += esumg[(size_t)b * CC + ch];
    float lse = 10.0f + logf(s);
    for (int n = tid; n < NN; n += 256)
        out[(size_t)b * NN + n] = lg[(size_t)b * NN + n] - lse;
}

// ===========================================================================
// Fallback: proven round-3-style mega-kernel (fp32), needs no workspace.
// ===========================================================================
__global__ __launch_bounds__(1024) void k_mega(
        const float* __restrict__ X, const float* __restrict__ Wnode,
        const float* __restrict__ Wfix, const float* __restrict__ Wstep,
        const float* __restrict__ Wout, const int* __restrict__ prev,
        const int* __restrict__ first, const void* __restrict__ mask,
        float* __restrict__ out) {
    int b = blockIdx.x, tid = threadIdx.x;
    __shared__ __align__(16) float cm[HH * 1024];
    __shared__ __align__(16) float qkl[HH * DD];
    __shared__ __align__(16) float qpart[8 * DD];
    __shared__ float xa[HH * DD];
    __shared__ float ge[DD], q[DD], sc[2 * DD], hd[DD], gl[DD], gqv[DD];
    __shared__ float red[16], invh[8];
    __shared__ int s_flag;
    const size_t xoff = (size_t)b * NN * DD;

    if (tid < 64) {
        const unsigned int* mw = (const unsigned int*)mask;
        unsigned int a0 = mw[tid], a1 = mw[tid + 64], a2 = mw[tid + 128], a3 = mw[tid + 192];
        int ii = (a0 <= 1u) && (a1 <= 1u) && (a2 <= 1u) && (a3 <= 1u);
        int ff = (a0 == 0u || a0 == 0x3F800000u) && (a1 == 0u || a1 == 0x3F800000u) &&
                 (a2 == 0u || a2 == 0x3F800000u) && (a3 == 0u || a3 == 0x3F800000u);
        int ai = __all(ii), af = __all(ff);
        if (tid == 0) s_flag = ai ? 1 : (af ? 2 : 0);
    }
    if (tid >= 256 && tid < 512) {
        int t = tid - 256;
        int src = (t < DD) ? first[b] : prev[b];
        sc[t] = X[xoff + (size_t)src * DD + (t & 127)];
    }
    {
        float4* red4 = (float4*)cm;
        int c = tid & 31, s = tid >> 5;
        const float4* Xr = (const float4*)(X + xoff);
        float4 acc = make_float4(0.f, 0.f, 0.f, 0.f);
        for (int n = s; n < NN; n += 32) {
            float4 v = Xr[n * 32 + c];
            acc.x += v.x; acc.y += v.y; acc.z += v.z; acc.w += v.w;
        }
        red4[s * 32 + c] = acc;
        __syncthreads();
        for (int st = 16; st >= 1; st >>= 1) {
            if (s < st) {
                float4 o = red4[(s + st) * 32 + c];
                float4 r = red4[s * 32 + c];
                r.x += o.x; r.y += o.y; r.z += o.z; r.w += o.w;
                red4[s * 32 + c] = r;
            }
            __syncthreads();
        }
        if (s == 0) {
            float4 r = red4[c];
            ge[4 * c] = r.x * (1.0f / NN); ge[4 * c + 1] = r.y * (1.0f / NN);
            ge[4 * c + 2] = r.z * (1.0f / NN); ge[4 * c + 3] = r.w * (1.0f / NN);
        }
        __syncthreads();
    }
    const int flag = s_flag;
    {
        int p = tid >> 7, d = tid & 127;
        float a = 0.f;
        for (int k = p * 16; k < p * 16 + 16; ++k) a += ge[k] * Wfix[k * DD + d];
        for (int k = p * 32; k < p * 32 + 32; ++k) a += sc[k] * Wstep[k * DD + d];
        qpart[p * DD + d] = a;
        __syncthreads();
        if (tid < DD) {
            float s = 0.f;
            for (int pp = 0; pp < 8; ++pp) s += qpart[pp * DD + tid];
            q[tid] = s;
        }
        __syncthreads();
        int d2 = tid >> 3, h = tid & 7;
        const float4* wr = (const float4*)(Wnode + (size_t)d2 * 384 + h * 16);
        float a2 = 0.f;
        for (int j4 = 0; j4 < 4; ++j4) {
            float4 w = wr[j4];
            a2 += w.x * q[h * 16 + 4 * j4]     + w.y * q[h * 16 + 4 * j4 + 1]
                + w.z * q[h * 16 + 4 * j4 + 2] + w.w * q[h * 16 + 4 * j4 + 3];
        }
        qkl[h * DD + d2] = 0.25f * a2;
        __syncthreads();
    }
    {
        int g = tid & 7;
        for (int it = 0; it < 8; ++it) {
            int n = it * 128 + (tid >> 3);
            if (n < NN) {
                float acc[HH] = {0.f, 0.f, 0.f, 0.f, 0.f, 0.f, 0.f, 0.f};
                const float4* xr = (const float4*)(X + xoff + (size_t)n * DD);
                for (int i = 0; i < 4; ++i) {
                    float4 v = xr[g + 8 * i];
                    int col = 4 * (g + 8 * i);
                    for (int h = 0; h < HH; ++h)
                        acc[h] += v.x * qkl[h * DD + col]     + v.y * qkl[h * DD + col + 1]
                                + v.z * qkl[h * DD + col + 2] + v.w * qkl[h * DD + col + 3];
                }
                for (int h = 0; h < HH; ++h) {
                    acc[h] += __shfl_xor(acc[h], 1, 8);
                    acc[h] += __shfl_xor(acc[h], 2, 8);
                    acc[h] += __shfl_xor(acc[h], 4, 8);
                }
                float val = acc[0];
                for (int h = 1; h < HH; ++h) val = (g == h) ? acc[h] : val;
                bool mk = get_mask(mask, flag, (size_t)b * NN + n);
                cm[g * 1024 + n] = mk ? NEG : val;
            }
        }
        __syncthreads();
    }
    {
        int h = tid >> 7, lane = tid & 127;
        float mx = -INFINITY;
        for (int n = lane; n < NN; n += 128) mx = fmaxf(mx, cm[h * 1024 + n]);
        for (int off = 32; off >= 1; off >>= 1) mx = fmaxf(mx, __shfl_xor(mx, off, 64));
        if ((tid & 63) == 0) red[tid >> 6] = mx;
        __syncthreads();
        float m_h = fmaxf(red[2 * h], red[2 * h + 1]);
        float sm = 0.f;
        for (int n = lane; n < NN; n += 128) {
            float p = __expf(cm[h * 1024 + n] - m_h);
            cm[h * 1024 + n] = p;
            sm += p;
        }
        for (int off = 32; off >= 1; off >>= 1) sm += __shfl_xor(sm, off, 64);
        __syncthreads();
        if ((tid & 63) == 0) red[tid >> 6] = sm;
        __syncthreads();
        if (tid < HH) invh[tid] = 1.0f / (red[2 * tid] + red[2 * tid + 1]);
        __syncthreads();
    }
    {
        int s = tid >> 7, d = tid & 127;
        float acc[HH] = {0.f, 0.f, 0.f, 0.f, 0.f, 0.f, 0.f, 0.f};
        for (int n = s; n < NN; n += 8) {
            float x = X[xoff + (size_t)n * DD + d];
            for (int h = 0; h < HH; ++h) acc[h] += cm[h * 1024 + n] * x;
        }
        __syncthreads();
        float* xp = cm;
        for (int h = 0; h < HH; ++h) xp[(s * HH + h) * DD + d] = acc[h];
        __syncthreads();
        if (s == 0) {
            for (int h = 0; h < HH; ++h) {
                float t = 0.f;
                for (int ss = 0; ss < 8; ++ss) t += xp[(ss * HH + h) * DD + d];
                xa[h * DD + d] = t * invh[h];
            }
        }
        __syncthreads();
    }
    {
        int p = tid >> 7, t = tid & 127;
        int h = t >> 4;
        float a = 0.f;
        for (int d = p * 16; d < p * 16 + 16; ++d)
            a += xa[h * DD + d] * Wnode[(size_t)d * 384 + 128 + t];
        qpart[p * DD + t] = a;
        __syncthreads();
        if (tid < DD) {
            float s = 0.f;
            for (int pp = 0; pp < 8; ++pp) s += qpart[pp * DD + tid];
            hd[tid] = s;
        }
        __syncthreads();
        a = 0.f;
        for (int k = p * 16; k < p * 16 + 16; ++k) a += hd[k] * Wout[(size_t)k * DD + t];
        qpart[p * DD + t] = a;
        __syncthreads();
        if (tid < DD) {
            float s = 0.f;
            for (int pp = 0; pp < 8; ++pp) s += qpart[pp * DD + tid];
            gl[tid] = s;
        }
        __syncthreads();
        const float4* wr = (const float4*)(Wnode + (size_t)t * 384 + 256 + p * 16);
        a = 0.f;
        for (int j4 = 0; j4 < 4; ++j4) {
            float4 w = wr[j4];
            int k = p * 16 + 4 * j4;
            a += w.x * gl[k] + w.y * gl[k + 1] + w.z * gl[k + 2] + w.w * gl[k + 3];
        }
        qpart[p * DD + t] = a;
        __syncthreads();
        if (tid < DD) {
            float s = 0.f;
            for (int pp = 0; pp < 8; ++pp) s += qpart[pp * DD + tid];
            gqv[tid] = s * 0.08838834764831845f;
        }
        __syncthreads();
    }
    {
        float* lg = qkl;
        int g = tid & 7;
        for (int it = 0; it < 8; ++it) {
            int n = it * 128 + (tid >> 3);
            if (n < NN) {
                const float4* xr = (const float4*)(X + xoff + (size_t)n * DD);
                float a = 0.f;
                for (int i = 0; i < 4; ++i) {
                    float4 v = xr[g + 8 * i];
                    int col = 4 * (g + 8 * i);
                    a += v.x * gqv[col] + v.y * gqv[col + 1] + v.z * gqv[col + 2] + v.w * gqv[col + 3];
                }
                a += __shfl_xor(a, 1, 8);
                a += __shfl_xor(a, 2, 8);
                a += __shfl_xor(a, 4, 8);
                if (g == 0) {
                    float lgt = 10.0f * tanhf(a);
                    lg[n] = get_mask(mask, flag, (size_t)b * NN + n) ? NEG : lgt;
                }
            }
        }
        __syncthreads();
        float v = (tid < NN) ? lg[tid] : -INFINITY;
        float mx = v;
        for (int off = 32; off >= 1; off >>= 1) mx = fmaxf(mx, __shfl_xor(mx, off, 64));
        if ((tid & 63) == 0) red[tid >> 6] = mx;
        __syncthreads();
        float m = red[0];
        for (int w = 1; w < 16; ++w) m = fmaxf(m, red[w]);
        float e = (tid < NN) ? __expf(v - m) : 0.f;
        float sm = e;
        for (int off = 32; off >= 1; off >>= 1) sm += __shfl_xor(sm, off, 64);
        __syncthreads();
        if ((tid & 63) == 0) red[tid >> 6] = sm;
        __syncthreads();
        float s2 = 0.f;
        for (int w = 0; w < 16; ++w) s2 += red[w];
        float lse = m + logf(s2);
        if (tid < NN) out[(size_t)b * NN + tid] = v - lse;
    }
}

// ---------------------------------------------------------------------------
extern "C" void kernel_launch(void* const* d_in, const int* in_sizes, int n_in,
                              void* d_out, int out_size, void* d_ws, size_t ws_size,
                              hipStream_t stream) {
    const float* X     = (const float*)d_in[0];
    const float* Wnode = (const float*)d_in[1];
    const float* Wfix  = (const float*)d_in[2];
    const float* Wstep = (const float*)d_in[3];
    const float* Wout  = (const float*)d_in[4];
    const int*   prev  = (const int*)d_in[5];
    const int*   first = (const int*)d_in[6];
    const void*  mask  = d_in[7];
    float* out = (float*)d_out;

    char* wsb = (char*)d_ws;
    int*   flag    = (int*)wsb;
    float* partial = (float*)(wsb + 256);                    // B*C*D   = 262144
    float* qkg     = partial + (size_t)BB * CC * DD;         // B*H*D   = 262144
    float* mqw     = qkg + (size_t)BB * HH * DD;             // B*C*H   = 16384
    float* sqw     = mqw + (size_t)BB * CC * HH;             // 16384
    float* pvp     = sqw + (size_t)BB * CC * HH;             // B*C*H*D = 2097152
    float* gqg     = pvp + (size_t)BB * CC * HH * DD;        // B*D     = 32768
    float* esumg   = gqg + (size_t)BB * DD;                  // B*C     = 2048
    float* lg      = esumg + (size_t)BB * CC;                // B*N     = 256000
    const size_t fl_end = 256 + sizeof(float) * (
        (size_t)BB * CC * DD + (size_t)BB * HH * DD + 2 * (size_t)BB * CC * HH +
        (size_t)BB * CC * HH * DD + (size_t)BB * DD + (size_t)BB * CC + (size_t)BB * NN);
    const size_t xb_off = (fl_end + 255) & ~(size_t)255;
    unsigned short* Xb = (unsigned short*)(wsb + xb_off);
    const size_t need = xb_off + (size_t)2 * BB * NN * DD;

    if (ws_size >= need) {
        k_stage <<<BB * CC, 256, 0, stream>>>(X, partial, Xb, (const unsigned int*)mask, flag);
        k_qk    <<<BB, 256, 0, stream>>>(X, Wfix, Wstep, Wnode, partial, prev, first, qkg);
        k_flash <<<BB * CC, 256, 0, stream>>>(Xb, qkg, mask, flag, mqw, sqw, pvp);
        k_comb  <<<BB, 256, 0, stream>>>(Wnode, Wout, mqw, sqw, pvp, gqg);
        k_logits<<<BB * CC, 256, 0, stream>>>(Xb, gqg, mask, flag, lg, esumg);
        k_final <<<BB, 256, 0, stream>>>(lg, esumg, out);
    } else {
        k_mega<<<BB, 1024, 0, stream>>>(X, Wnode, Wfix, Wstep, Wout,
                                        prev, first, mask, out);
    }
}

// Round 13
// 121.996 us; speedup vs baseline: 1.0769x; 1.0769x over previous
//
#include <hip/hip_runtime.h>
#include <math.h>

#define BB 256
#define NN 1000
#define DD 128
#define HH 8
#define CC 8            // chunks per batch element
#define RC 125          // rows per static chunk (mask fill)
#define NEG -1e9f

__device__ __forceinline__ bool get_mask(const void* m, int flag, size_t idx) {
    if (flag == 1) return ((const int*)m)[idx] != 0;
    if (flag == 2) return ((const float*)m)[idx] != 0.0f;
    return ((const unsigned char*)m)[idx] != 0;
}

// ===========================================================================
// K1: mean partials. grid BB*CC = 2048 blocks (8/CU), 256 thr.
// Pure fp32 stream of X (131 MB). Block 0 also detects mask dtype.
// ===========================================================================
__global__ __launch_bounds__(256) void k_mean(
        const float* __restrict__ X, float* __restrict__ partial,
        const unsigned int* __restrict__ maskw, int* __restrict__ flag) {
    int bid = blockIdx.x, tid = threadIdx.x;
    int b = bid >> 3, ch = bid & 7;
    if (bid == 0 && tid < 64) {
        unsigned int a0 = maskw[tid], a1 = maskw[tid + 64],
                     a2 = maskw[tid + 128], a3 = maskw[tid + 192];
        int ii = (a0 <= 1u) && (a1 <= 1u) && (a2 <= 1u) && (a3 <= 1u);
        int ff = (a0 == 0u || a0 == 0x3F800000u) && (a1 == 0u || a1 == 0x3F800000u) &&
                 (a2 == 0u || a2 == 0x3F800000u) && (a3 == 0u || a3 == 0x3F800000u);
        int ai = __all(ii), af = __all(ff);
        if (tid == 0) *flag = ai ? 1 : (af ? 2 : 0);
    }
    int c = tid & 31, s = tid >> 5;
    const float4* Xr = (const float4*)(X + (size_t)b * NN * DD);
    float4 acc = make_float4(0.f, 0.f, 0.f, 0.f);
    int n0 = ch * RC;
    for (int nl = s; nl < RC; nl += 8) {
        float4 v = Xr[(n0 + nl) * 32 + c];
        acc.x += v.x; acc.y += v.y; acc.z += v.z; acc.w += v.w;
    }
    __shared__ float4 red[8][32];
    red[s][c] = acc;
    __syncthreads();
    for (int st = 4; st >= 1; st >>= 1) {
        if (s < st) {
            float4 o = red[s + st][c];
            red[s][c].x += o.x; red[s][c].y += o.y;
            red[s][c].z += o.z; red[s][c].w += o.w;
        }
        __syncthreads();
    }
    if (s == 0) {
        float4 r = red[0][c];
        float* outp = partial + ((size_t)b * CC + ch) * DD + 4 * c;
        outp[0] = r.x; outp[1] = r.y; outp[2] = r.z; outp[3] = r.w;
    }
}

// ===========================================================================
// K2: per-b query + qk vectors + compaction of unmasked row indices.
// grid BB, 256 thr.
// ===========================================================================
__global__ __launch_bounds__(256) void k_qk(
        const float* __restrict__ X, const float* __restrict__ Wfix,
        const float* __restrict__ Wstep, const float* __restrict__ Wnode,
        const float* __restrict__ partial, const int* __restrict__ prev,
        const int* __restrict__ first, const void* __restrict__ mask,
        const int* __restrict__ flag, float* __restrict__ qkg,
        unsigned short* __restrict__ cidx, int* __restrict__ cnt) {
    int b = blockIdx.x, tid = threadIdx.x;
    const size_t xoff = (size_t)b * NN * DD;
    const int f = *flag;
    __shared__ float ge[DD], sc[2 * DD], qv[DD], qp[2][DD];
    __shared__ int wbase[4];
    __shared__ int s_total;

    if (tid < DD) {
        float g = 0.f;
        #pragma unroll
        for (int ch = 0; ch < CC; ++ch) g += partial[((size_t)b * CC + ch) * DD + tid];
        ge[tid] = g * (1.0f / NN);
    }
    {
        int src = (tid < DD) ? first[b] : prev[b];
        sc[tid] = X[xoff + (size_t)src * DD + (tid & 127)];
    }
    if (tid == 0) s_total = 0;
    __syncthreads();
    int p = tid >> 7, d = tid & 127;
    {
        float a = 0.f;
        #pragma unroll 4
        for (int k = p * 64; k < p * 64 + 64; ++k)      a += ge[k] * Wfix[(size_t)k * DD + d];
        #pragma unroll 4
        for (int k = p * 128; k < p * 128 + 128; ++k)   a += sc[k] * Wstep[(size_t)k * DD + d];
        qp[p][d] = a;
    }
    __syncthreads();
    if (tid < DD) qv[tid] = qp[0][tid] + qp[1][tid];
    __syncthreads();
    {
        const float* wrow = Wnode + (size_t)d * 384;
        #pragma unroll
        for (int h = p * 4; h < p * 4 + 4; ++h) {
            const float4* wr = (const float4*)(wrow + h * 16);
            float a = 0.f;
            #pragma unroll
            for (int j4 = 0; j4 < 4; ++j4) {
                float4 w = wr[j4];
                a += w.x * qv[h * 16 + 4 * j4]     + w.y * qv[h * 16 + 4 * j4 + 1]
                   + w.z * qv[h * 16 + 4 * j4 + 2] + w.w * qv[h * 16 + 4 * j4 + 3];
            }
            qkg[((size_t)b * HH + h) * DD + d] = 0.25f * a;   // 1/sqrt(16)
        }
    }
    // ---- compaction: deterministic ballot prefix over 4 segments of 256 ----
    int w = tid >> 6, lane = tid & 63;
    for (int seg = 0; seg < 4; ++seg) {
        int n = seg * 256 + tid;
        bool un = (n < NN) && !get_mask(mask, f, (size_t)b * NN + n);
        unsigned long long bal = __ballot(un);
        if (lane == 0) wbase[w] = __popcll(bal);
        __syncthreads();
        int base = s_total;
        for (int ww = 0; ww < w; ++ww) base += wbase[ww];
        int myoff = __popcll(bal & ((1ULL << lane) - 1ULL));
        if (un) cidx[(size_t)b * 1024 + base + myoff] = (unsigned short)n;
        __syncthreads();
        if (tid == 0) s_total += wbase[0] + wbase[1] + wbase[2] + wbase[3];
        __syncthreads();
    }
    if (tid == 0) cnt[b] = s_total;
}

// ===========================================================================
// K3: fused compat -> exp (no max, clamp 80) -> PV, over compacted rows only.
// grid BB*CC = 2048, 256 thr, 16 lanes per row. X read ONCE.
// Outputs unnormalized pvp[b][ch][h][d] and sums sqw[b][ch][h].
// ===========================================================================
__global__ __launch_bounds__(256, 4) void k_flash(
        const float* __restrict__ X, const float* __restrict__ qkg,
        const unsigned short* __restrict__ cidx, const int* __restrict__ cnt,
        float* __restrict__ sqw, float* __restrict__ pvp) {
    int bid = blockIdx.x, tid = threadIdx.x;
    int b = bid >> 3, ch = bid & 7;
    const size_t xoff = (size_t)b * NN * DD;

    __shared__ __align__(16) float qks[HH][DD];      // 4 KB
    __shared__ __align__(16) float redpv[4][HH][DD]; // 16 KB
    __shared__ float redS[4][HH];

    for (int i = tid; i < HH * DD; i += 256)
        qks[i >> 7][i & 127] = qkg[(size_t)b * HH * DD + i];
    __syncthreads();

    const int g = tid & 15;       // col group: cols 8g..8g+7
    const int r = tid >> 4;       // row slot [0,16)
    const int w = tid >> 6;       // wave [0,4)

    int total = cnt[b];
    int rpc = (total + CC - 1) / CC;
    int k0 = ch * rpc;
    int k1 = k0 + rpc; if (k1 > total) k1 = total;
    int len = k1 - k0; if (len < 0) len = 0;
    int iters = (len + 15) >> 4;

    float acc[HH][8];
    #pragma unroll
    for (int h = 0; h < HH; ++h)
        #pragma unroll
        for (int j = 0; j < 8; ++j) acc[h][j] = 0.f;
    float S[HH] = {0.f, 0.f, 0.f, 0.f, 0.f, 0.f, 0.f, 0.f};

    for (int it = 0; it < iters; ++it) {
        int k = k0 + it * 16 + r;
        if (k < k1) {                       // uniform across each 16-lane group
            int n = cidx[(size_t)b * 1024 + k];
            const float4* xr = (const float4*)(X + xoff + (size_t)n * DD + 8 * g);
            float4 v0 = xr[0], v1 = xr[1];
            float v[8] = {v0.x, v0.y, v0.z, v0.w, v1.x, v1.y, v1.z, v1.w};
            float cp[HH];
            #pragma unroll
            for (int h = 0; h < HH; ++h) {
                const float4* qr = (const float4*)&qks[h][8 * g];
                float4 q0 = qr[0], q1 = qr[1];
                cp[h] = v[0] * q0.x + v[1] * q0.y + v[2] * q0.z + v[3] * q0.w
                      + v[4] * q1.x + v[5] * q1.y + v[6] * q1.z + v[7] * q1.w;
            }
            #pragma unroll
            for (int h = 0; h < HH; ++h) {
                cp[h] += __shfl_xor(cp[h], 1, 16);
                cp[h] += __shfl_xor(cp[h], 2, 16);
                cp[h] += __shfl_xor(cp[h], 4, 16);
                cp[h] += __shfl_xor(cp[h], 8, 16);
            }
            #pragma unroll
            for (int h = 0; h < HH; ++h) {
                float pe = __expf(fminf(cp[h], 80.f));   // no-max softmax, safe clamp
                S[h] += pe;
                #pragma unroll
                for (int j = 0; j < 8; ++j) acc[h][j] += pe * v[j];
            }
        }
    }
    // reduce across the 4 row-slots within each wave (lanes ^16, ^32)
    #pragma unroll
    for (int h = 0; h < HH; ++h) {
        S[h] += __shfl_xor(S[h], 16, 64);
        S[h] += __shfl_xor(S[h], 32, 64);
        #pragma unroll
        for (int j = 0; j < 8; ++j) {
            acc[h][j] += __shfl_xor(acc[h][j], 16, 64);
            acc[h][j] += __shfl_xor(acc[h][j], 32, 64);
        }
    }
    if ((tid & 63) < 16) {                  // r_lo == 0 lanes hold wave totals
        #pragma unroll
        for (int h = 0; h < HH; ++h) {
            *((float4*)&redpv[w][h][8 * g])     =
                make_float4(acc[h][0], acc[h][1], acc[h][2], acc[h][3]);
            *((float4*)&redpv[w][h][8 * g + 4]) =
                make_float4(acc[h][4], acc[h][5], acc[h][6], acc[h][7]);
        }
        if (g == 0) {
            #pragma unroll
            for (int h = 0; h < HH; ++h) redS[w][h] = S[h];
        }
    }
    __syncthreads();
    for (int idx = tid; idx < HH * DD; idx += 256) {
        int h = idx >> 7, d = idx & 127;
        pvp[(((size_t)b * CC + ch) * HH + h) * DD + d] =
            redpv[0][h][d] + redpv[1][h][d] + redpv[2][h][d] + redpv[3][h][d];
    }
    if (tid < HH)
        sqw[((size_t)b * CC + ch) * HH + tid] =
            redS[0][tid] + redS[1][tid] + redS[2][tid] + redS[3][tid];
}

// ===========================================================================
// K4: per-b combine (plain sums, no rescale) -> heads -> glimpse -> gq.
// grid BB, 256 thr.
// ===========================================================================
__global__ __launch_bounds__(256) void k_comb(
        const float* __restrict__ Wnode, const float* __restrict__ Wout,
        const float* __restrict__ sqw, const float* __restrict__ pvp,
        float* __restrict__ gqg) {
    int b = blockIdx.x, tid = threadIdx.x;
    __shared__ float Sh[HH];
    __shared__ float xa[HH][DD], qp[2][DD], hd[DD], gl[DD];
    if (tid < HH) {
        float S = 0.f;
        #pragma unroll
        for (int ch = 0; ch < CC; ++ch) S += sqw[((size_t)b * CC + ch) * HH + tid];
        Sh[tid] = 1.0f / S;
    }
    __syncthreads();
    for (int idx = tid; idx < HH * DD; idx += 256) {
        int h = idx >> 7, d = idx & 127;
        float a = 0.f;
        #pragma unroll
        for (int ch = 0; ch < CC; ++ch)
            a += pvp[(((size_t)b * CC + ch) * HH + h) * DD + d];
        xa[h][d] = a * Sh[h];
    }
    __syncthreads();
    int p = tid >> 7, t = tid & 127;
    {
        int h = t >> 4;
        float a = 0.f;
        #pragma unroll 4
        for (int d = p * 64; d < p * 64 + 64; ++d)
            a += xa[h][d] * Wnode[(size_t)d * 384 + 128 + t];
        qp[p][t] = a;
    }
    __syncthreads();
    if (tid < DD) hd[tid] = qp[0][tid] + qp[1][tid];
    __syncthreads();
    {
        float a = 0.f;
        #pragma unroll 4
        for (int k = p * 64; k < p * 64 + 64; ++k) a += hd[k] * Wout[(size_t)k * DD + t];
        qp[p][t] = a;
    }
    __syncthreads();
    if (tid < DD) gl[tid] = qp[0][tid] + qp[1][tid];
    __syncthreads();
    {
        const float4* wr = (const float4*)(Wnode + (size_t)t * 384 + 256 + p * 64);
        float a = 0.f;
        #pragma unroll
        for (int j4 = 0; j4 < 16; ++j4) {
            float4 w = wr[j4];
            int k = p * 64 + 4 * j4;
            a += w.x * gl[k] + w.y * gl[k + 1] + w.z * gl[k + 2] + w.w * gl[k + 3];
        }
        qp[p][t] = a;
    }
    __syncthreads();
    if (tid < DD) gqg[(size_t)b * DD + tid] = (qp[0][tid] + qp[1][tid]) * 0.08838834764831845f;
}

// ===========================================================================
// K5: logits over compacted rows only + NEG fill for masked rows.
// grid BB*CC = 2048, 256 thr.
// ===========================================================================
__global__ __launch_bounds__(256, 8) void k_logits(
        const float* __restrict__ X, const float* __restrict__ gqg,
        const void* __restrict__ mask, const int* __restrict__ flag,
        const unsigned short* __restrict__ cidx, const int* __restrict__ cnt,
        float* __restrict__ lg, float* __restrict__ esumg) {
    int bid = blockIdx.x, tid = threadIdx.x;
    int b = bid >> 3, ch = bid & 7;
    const size_t xoff = (size_t)b * NN * DD;
    const int f = *flag;
    __shared__ float gqv[DD];
    __shared__ float redw[4];
    if (tid < DD) gqv[tid] = gqg[(size_t)b * DD + tid];
    __syncthreads();
    // masked rows in this block's static range -> NEG (disjoint from compacted set)
    if (tid < RC) {
        int n = ch * RC + tid;
        if (get_mask(mask, f, (size_t)b * NN + n)) lg[(size_t)b * NN + n] = NEG;
    }
    // compacted (unmasked) rows: 8 lanes per row
    int total = cnt[b];
    int rpc = (total + CC - 1) / CC;
    int k0 = ch * rpc, k1 = k0 + rpc; if (k1 > total) k1 = total;
    int len = k1 - k0; if (len < 0) len = 0;
    int iters = (len + 31) >> 5;
    int g = tid & 7, rr = tid >> 3;
    float esum = 0.f;
    for (int it = 0; it < iters; ++it) {
        int k = k0 + it * 32 + rr;
        if (k < k1) {
            int n = cidx[(size_t)b * 1024 + k];
            const float4* xr = (const float4*)(X + xoff + (size_t)n * DD);
            float a = 0.f;
            #pragma unroll
            for (int i = 0; i < 4; ++i) {
                float4 v = xr[g + 8 * i];
                int col = 4 * (g + 8 * i);
                a += v.x * gqv[col] + v.y * gqv[col + 1]
                   + v.z * gqv[col + 2] + v.w * gqv[col + 3];
            }
            a += __shfl_xor(a, 1, 8);
            a += __shfl_xor(a, 2, 8);
            a += __shfl_xor(a, 4, 8);
            if (g == 0) {
                float l = 10.0f * tanhf(a);
                lg[(size_t)b * NN + n] = l;
                esum += __expf(l - 10.0f);      // logits <= 10 always
            }
        }
    }
    #pragma unroll
    for (int off = 32; off >= 1; off >>= 1) esum += __shfl_xor(esum, off, 64);
    if ((tid & 63) == 0) redw[tid >> 6] = esum;
    __syncthreads();
    if (tid == 0) esumg[(size_t)b * CC + ch] = redw[0] + redw[1] + redw[2] + redw[3];
}

// ===========================================================================
// K6: lse + store. grid BB, 256 thr.
// ===========================================================================
__global__ __launch_bounds__(256) void k_final(
        const float* __restrict__ lg, const float* __restrict__ esumg,
        float* __restrict__ out) {
    int b = blockIdx.x, tid = threadIdx.x;
    float s = 0.f;
    #pragma unroll
    for (int ch = 0; ch < CC; ++ch) s += esumg[(size_t)b * CC + ch];
    float lse = 10.0f + logf(s);
    for (int n = tid; n < NN; n += 256)
        out[(size_t)b * NN + n] = lg[(size_t)b * NN + n] - lse;
}

// ===========================================================================
// Fallback: proven mega-kernel (fp32), needs no workspace.
// ===========================================================================
__global__ __launch_bounds__(1024) void k_mega(
        const float* __restrict__ X, const float* __restrict__ Wnode,
        const float* __restrict__ Wfix, const float* __restrict__ Wstep,
        const float* __restrict__ Wout, const int* __restrict__ prev,
        const int* __restrict__ first, const void* __restrict__ mask,
        float* __restrict__ out) {
    int b = blockIdx.x, tid = threadIdx.x;
    __shared__ __align__(16) float cm[HH * 1024];
    __shared__ __align__(16) float qkl[HH * DD];
    __shared__ __align__(16) float qpart[8 * DD];
    __shared__ float xa[HH * DD];
    __shared__ float ge[DD], q[DD], sc[2 * DD], hd[DD], gl[DD], gqv[DD];
    __shared__ float red[16], invh[8];
    __shared__ int s_flag;
    const size_t xoff = (size_t)b * NN * DD;

    if (tid < 64) {
        const unsigned int* mw = (const unsigned int*)mask;
        unsigned int a0 = mw[tid], a1 = mw[tid + 64], a2 = mw[tid + 128], a3 = mw[tid + 192];
        int ii = (a0 <= 1u) && (a1 <= 1u) && (a2 <= 1u) && (a3 <= 1u);
        int ff = (a0 == 0u || a0 == 0x3F800000u) && (a1 == 0u || a1 == 0x3F800000u) &&
                 (a2 == 0u || a2 == 0x3F800000u) && (a3 == 0u || a3 == 0x3F800000u);
        int ai = __all(ii), af = __all(ff);
        if (tid == 0) s_flag = ai ? 1 : (af ? 2 : 0);
    }
    if (tid >= 256 && tid < 512) {
        int t = tid - 256;
        int src = (t < DD) ? first[b] : prev[b];
        sc[t] = X[xoff + (size_t)src * DD + (t & 127)];
    }
    {
        float4* red4 = (float4*)cm;
        int c = tid & 31, s = tid >> 5;
        const float4* Xr = (const float4*)(X + xoff);
        float4 acc = make_float4(0.f, 0.f, 0.f, 0.f);
        for (int n = s; n < NN; n += 32) {
            float4 v = Xr[n * 32 + c];
            acc.x += v.x; acc.y += v.y; acc.z += v.z; acc.w += v.w;
        }
        red4[s * 32 + c] = acc;
        __syncthreads();
        for (int st = 16; st >= 1; st >>= 1) {
            if (s < st) {
                float4 o = red4[(s + st) * 32 + c];
                float4 r = red4[s * 32 + c];
                r.x += o.x; r.y += o.y; r.z += o.z; r.w += o.w;
                red4[s * 32 + c] = r;
            }
            __syncthreads();
        }
        if (s == 0) {
            float4 r = red4[c];
            ge[4 * c] = r.x * (1.0f / NN); ge[4 * c + 1] = r.y * (1.0f / NN);
            ge[4 * c + 2] = r.z * (1.0f / NN); ge[4 * c + 3] = r.w * (1.0f / NN);
        }
        __syncthreads();
    }
    const int flag = s_flag;
    {
        int p = tid >> 7, d = tid & 127;
        float a = 0.f;
        for (int k = p * 16; k < p * 16 + 16; ++k) a += ge[k] * Wfix[k * DD + d];
        for (int k = p * 32; k < p * 32 + 32; ++k) a += sc[k] * Wstep[k * DD + d];
        qpart[p * DD + d] = a;
        __syncthreads();
        if (tid < DD) {
            float s = 0.f;
            for (int pp = 0; pp < 8; ++pp) s += qpart[pp * DD + tid];
            q[tid] = s;
        }
        __syncthreads();
        int d2 = tid >> 3, h = tid & 7;
        const float4* wr = (const float4*)(Wnode + (size_t)d2 * 384 + h * 16);
        float a2 = 0.f;
        for (int j4 = 0; j4 < 4; ++j4) {
            float4 w = wr[j4];
            a2 += w.x * q[h * 16 + 4 * j4]     + w.y * q[h * 16 + 4 * j4 + 1]
                + w.z * q[h * 16 + 4 * j4 + 2] + w.w * q[h * 16 + 4 * j4 + 3];
        }
        qkl[h * DD + d2] = 0.25f * a2;
        __syncthreads();
    }
    {
        int g = tid & 7;
        for (int it = 0; it < 8; ++it) {
            int n = it * 128 + (tid >> 3);
            if (n < NN) {
                float acc[HH] = {0.f, 0.f, 0.f, 0.f, 0.f, 0.f, 0.f, 0.f};
                const float4* xr = (const float4*)(X + xoff + (size_t)n * DD);
                for (int i = 0; i < 4; ++i) {
                    float4 v = xr[g + 8 * i];
                    int col = 4 * (g + 8 * i);
                    for (int h = 0; h < HH; ++h)
                        acc[h] += v.x * qkl[h * DD + col]     + v.y * qkl[h * DD + col + 1]
                                + v.z * qkl[h * DD + col + 2] + v.w * qkl[h * DD + col + 3];
                }
                for (int h = 0; h < HH; ++h) {
                    acc[h] += __shfl_xor(acc[h], 1, 8);
                    acc[h] += __shfl_xor(acc[h], 2, 8);
                    acc[h] += __shfl_xor(acc[h], 4, 8);
                }
                float val = acc[0];
                for (int h = 1; h < HH; ++h) val = (g == h) ? acc[h] : val;
                bool mk = get_mask(mask, flag, (size_t)b * NN + n);
                cm[g * 1024 + n] = mk ? NEG : val;
            }
        }
        __syncthreads();
    }
    {
        int h = tid >> 7, lane = tid & 127;
        float mx = -INFINITY;
        for (int n = lane; n < NN; n += 128) mx = fmaxf(mx, cm[h * 1024 + n]);
        for (int off = 32; off >= 1; off >>= 1) mx = fmaxf(mx, __shfl_xor(mx, off, 64));
        if ((tid & 63) == 0) red[tid >> 6] = mx;
        __syncthreads();
        float m_h = fmaxf(red[2 * h], red[2 * h + 1]);
        float sm = 0.f;
        for (int n = lane; n < NN; n += 128) {
            float p = __expf(cm[h * 1024 + n] - m_h);
            cm[h * 1024 + n] = p;
            sm += p;
        }
        for (int off = 32; off >= 1; off >>= 1) sm += __shfl_xor(sm, off, 64);
        __syncthreads();
        if ((tid & 63) == 0) red[tid >> 6] = sm;
        __syncthreads();
        if (tid < HH) invh[tid] = 1.0f / (red[2 * tid] + red[2 * tid + 1]);
        __syncthreads();
    }
    {
        int s = tid >> 7, d = tid & 127;
        float acc[HH] = {0.f, 0.f, 0.f, 0.f, 0.f, 0.f, 0.f, 0.f};
        for (int n = s; n < NN; n += 8) {
            float x = X[xoff + (size_t)n * DD + d];
            for (int h = 0; h < HH; ++h) acc[h] += cm[h * 1024 + n] * x;
        }
        __syncthreads();
        float* xp = cm;
        for (int h = 0; h < HH; ++h) xp[(s * HH + h) * DD + d] = acc[h];
        __syncthreads();
        if (s == 0) {
            for (int h = 0; h < HH; ++h) {
                float t = 0.f;
                for (int ss = 0; ss < 8; ++ss) t += xp[(ss * HH + h) * DD + d];
                xa[h * DD + d] = t * invh[h];
            }
        }
        __syncthreads();
    }
    {
        int p = tid >> 7, t = tid & 127;
        int h = t >> 4;
        float a = 0.f;
        for (int d = p * 16; d < p * 16 + 16; ++d)
            a += xa[h * DD + d] * Wnode[(size_t)d * 384 + 128 + t];
        qpart[p * DD + t] = a;
        __syncthreads();
        if (tid < DD) {
            float s = 0.f;
            for (int pp = 0; pp < 8; ++pp) s += qpart[pp * DD + tid];
            hd[tid] = s;
        }
        __syncthreads();
        a = 0.f;
        for (int k = p * 16; k < p * 16 + 16; ++k) a += hd[k] * Wout[(size_t)k * DD + t];
        qpart[p * DD + t] = a;
        __syncthreads();
        if (tid < DD) {
            float s = 0.f;
            for (int pp = 0; pp < 8; ++pp) s += qpart[pp * DD + tid];
            gl[tid] = s;
        }
        __syncthreads();
        const float4* wr = (const float4*)(Wnode + (size_t)t * 384 + 256 + p * 16);
        a = 0.f;
        for (int j4 = 0; j4 < 4; ++j4) {
            float4 w = wr[j4];
            int k = p * 16 + 4 * j4;
            a += w.x * gl[k] + w.y * gl[k + 1] + w.z * gl[k + 2] + w.w * gl[k + 3];
        }
        qpart[p * DD + t] = a;
        __syncthreads();
        if (tid < DD) {
            float s = 0.f;
            for (int pp = 0; pp < 8; ++pp) s += qpart[pp * DD + tid];
            gqv[tid] = s * 0.08838834764831845f;
        }
        __syncthreads();
    }
    {
        float* lg = qkl;
        int g = tid & 7;
        for (int it = 0; it < 8; ++it) {
            int n = it * 128 + (tid >> 3);
            if (n < NN) {
                const float4* xr = (const float4*)(X + xoff + (size_t)n * DD);
                float a = 0.f;
                for (int i = 0; i < 4; ++i) {
                    float4 v = xr[g + 8 * i];
                    int col = 4 * (g + 8 * i);
                    a += v.x * gqv[col] + v.y * gqv[col + 1] + v.z * gqv[col + 2] + v.w * gqv[col + 3];
                }
                a += __shfl_xor(a, 1, 8);
                a += __shfl_xor(a, 2, 8);
                a += __shfl_xor(a, 4, 8);
                if (g == 0) {
                    float lgt = 10.0f * tanhf(a);
                    lg[n] = get_mask(mask, flag, (size_t)b * NN + n) ? NEG : lgt;
                }
            }
        }
        __syncthreads();
        float v = (tid < NN) ? lg[tid] : -INFINITY;
        float mx = v;
        for (int off = 32; off >= 1; off >>= 1) mx = fmaxf(mx, __shfl_xor(mx, off, 64));
        if ((tid & 63) == 0) red[tid >> 6] = mx;
        __syncthreads();
        float m = red[0];
        for (int w = 1; w < 16; ++w) m = fmaxf(m, red[w]);
        float e = (tid < NN) ? __expf(v - m) : 0.f;
        float sm = e;
        for (int off = 32; off >= 1; off >>= 1) sm += __shfl_xor(sm, off, 64);
        __syncthreads();
        if ((tid & 63) == 0) red[tid >> 6] = sm;
        __syncthreads();
        float s2 = 0.f;
        for (int w = 0; w < 16; ++w) s2 += red[w];
        float lse = m + logf(s2);
        if (tid < NN) out[(size_t)b * NN + tid] = v - lse;
    }
}

// ---------------------------------------------------------------------------
extern "C" void kernel_launch(void* const* d_in, const int* in_sizes, int n_in,
                              void* d_out, int out_size, void* d_ws, size_t ws_size,
                              hipStream_t stream) {
    const float* X     = (const float*)d_in[0];
    const float* Wnode = (const float*)d_in[1];
    const float* Wfix  = (const float*)d_in[2];
    const float* Wstep = (const float*)d_in[3];
    const float* Wout  = (const float*)d_in[4];
    const int*   prev  = (const int*)d_in[5];
    const int*   first = (const int*)d_in[6];
    const void*  mask  = d_in[7];
    float* out = (float*)d_out;

    char* wsb = (char*)d_ws;
    int*   flag    = (int*)wsb;
    float* partial = (float*)(wsb + 256);                    // B*C*D   = 262144
    float* qkg     = partial + (size_t)BB * CC * DD;         // B*H*D   = 262144
    float* sqw     = qkg + (size_t)BB * HH * DD;             // B*C*H   = 16384
    float* pvp     = sqw + (size_t)BB * CC * HH;             // B*C*H*D = 2097152
    float* gqg     = pvp + (size_t)BB * CC * HH * DD;        // B*D     = 32768
    float* esumg   = gqg + (size_t)BB * DD;                  // B*C     = 2048
    float* lg      = esumg + (size_t)BB * CC;                // B*N     = 256000
    int*   cnt     = (int*)(lg + (size_t)BB * NN);           // B ints
    unsigned short* cidx = (unsigned short*)(cnt + BB);      // B*1024 ushort
    const size_t need = 256 + sizeof(float) * (
        (size_t)BB * CC * DD + (size_t)BB * HH * DD + (size_t)BB * CC * HH +
        (size_t)BB * CC * HH * DD + (size_t)BB * DD + (size_t)BB * CC + (size_t)BB * NN)
        + sizeof(int) * BB + sizeof(unsigned short) * (size_t)BB * 1024;

    if (ws_size >= need) {
        k_mean  <<<BB * CC, 256, 0, stream>>>(X, partial, (const unsigned int*)mask, flag);
        k_qk    <<<BB, 256, 0, stream>>>(X, Wfix, Wstep, Wnode, partial, prev, first,
                                         mask, flag, qkg, cidx, cnt);
        k_flash <<<BB * CC, 256, 0, stream>>>(X, qkg, cidx, cnt, sqw, pvp);
        k_comb  <<<BB, 256, 0, stream>>>(Wnode, Wout, sqw, pvp, gqg);
        k_logits<<<BB * CC, 256, 0, stream>>>(X, gqg, mask, flag, cidx, cnt, lg, esumg);
        k_final <<<BB, 256, 0, stream>>>(lg, esumg, out);
    } else {
        k_mega<<<BB, 1024, 0, stream>>>(X, Wnode, Wfix, Wstep, Wout,
                                        prev, first, mask, out);
    }
}

// Round 14
// 107.475 us; speedup vs baseline: 1.2223x; 1.1351x over previous
//
#include <hip/hip_runtime.h>
#include <math.h>

#define BB 256
#define NN 1000
#define DD 128
#define HH 8
#define QQ 4            // sibling blocks per batch element
#define RQ 250          // rows per quarter
#define NEG -1e9f

// per-b sync slots (16 ints = 64 B per b, zeroed each call)
#define SY_CNTA 0
#define SY_QK   1
#define SY_CNTC 2
#define SY_GQ   3
#define SY_CNTE 4

__device__ __forceinline__ bool get_mask(const void* m, int flag, size_t idx) {
    if (flag == 1) return ((const int*)m)[idx] != 0;
    if (flag == 2) return ((const float*)m)[idx] != 0.0f;
    return ((const unsigned char*)m)[idx] != 0;
}

__device__ __forceinline__ void sy_arrive(int* p) {
    __builtin_amdgcn_fence(__ATOMIC_RELEASE, "agent");
    __hip_atomic_fetch_add(p, 1, __ATOMIC_RELAXED, __HIP_MEMORY_SCOPE_AGENT);
}
__device__ __forceinline__ void sy_set(int* p) {
    __builtin_amdgcn_fence(__ATOMIC_RELEASE, "agent");
    __hip_atomic_store(p, 1, __ATOMIC_RELAXED, __HIP_MEMORY_SCOPE_AGENT);
}
__device__ __forceinline__ void sy_wait(int* p, int tgt) {
    while (__hip_atomic_load(p, __ATOMIC_RELAXED, __HIP_MEMORY_SCOPE_AGENT) < tgt)
        __builtin_amdgcn_s_sleep(8);
    __builtin_amdgcn_fence(__ATOMIC_ACQUIRE, "agent");
}

// ===========================================================================
// Single fused kernel: grid BB*QQ = 1024 blocks (b,q), 256 thr, 4 blocks/CU
// (all-resident; gated on host). Per-b spin syncs replace kernel boundaries.
// ===========================================================================
__global__ __launch_bounds__(256, 4) void k_one(
        const float* __restrict__ X, const float* __restrict__ Wnode,
        const float* __restrict__ Wfix, const float* __restrict__ Wstep,
        const float* __restrict__ Wout, const int* __restrict__ prev,
        const int* __restrict__ first, const void* __restrict__ mask,
        int* __restrict__ syg, float* __restrict__ partial,
        float* __restrict__ qkg, float* __restrict__ sqw,
        float* __restrict__ pvp, float* __restrict__ gqg,
        float* __restrict__ esumg, float* __restrict__ out) {
    const int bid = blockIdx.x, tid = threadIdx.x;
    const int b = bid >> 2, q = bid & 3;
    const int n0 = q * RQ;
    const size_t xoff = (size_t)b * NN * DD;
    int* sy = syg + b * 16;

    __shared__ __align__(16) unsigned char pool[16384];   // phase-overlaid
    __shared__ __align__(16) float qks[HH][DD];           // 4 KB
    __shared__ float gqv[DD];
    __shared__ float lgl[256];
    __shared__ unsigned short cidxL[256];
    __shared__ float redS[4][HH];
    __shared__ float Sh[HH];
    __shared__ float redw[4];
    __shared__ int wbase[4];
    __shared__ int s_flag, s_cnt;
    float* poolf = (float*)pool;

    // ---- P0: mask dtype detect (every block, local) ----
    if (tid < 64) {
        const unsigned int* mw = (const unsigned int*)mask;
        unsigned int a0 = mw[tid], a1 = mw[tid + 64], a2 = mw[tid + 128], a3 = mw[tid + 192];
        int ii = (a0 <= 1u) && (a1 <= 1u) && (a2 <= 1u) && (a3 <= 1u);
        int ff = (a0 == 0u || a0 == 0x3F800000u) && (a1 == 0u || a1 == 0x3F800000u) &&
                 (a2 == 0u || a2 == 0x3F800000u) && (a3 == 0u || a3 == 0x3F800000u);
        int ai = __all(ii), af = __all(ff);
        if (tid == 0) s_flag = ai ? 1 : (af ? 2 : 0);
    }

    // ---- P1a: mean partial over own quarter (the one HBM pass over X) ----
    {
        float4* red4 = (float4*)pool;                     // [8][32]
        int c = tid & 31, s = tid >> 5;
        const float4* Xr = (const float4*)(X + xoff);
        float4 acc = make_float4(0.f, 0.f, 0.f, 0.f);
        for (int nl = s; nl < RQ; nl += 8) {
            float4 v = Xr[(n0 + nl) * 32 + c];
            acc.x += v.x; acc.y += v.y; acc.z += v.z; acc.w += v.w;
        }
        red4[s * 32 + c] = acc;
        __syncthreads();
        for (int st = 4; st >= 1; st >>= 1) {
            if (s < st) {
                float4 o = red4[(s + st) * 32 + c];
                float4 r = red4[s * 32 + c];
                r.x += o.x; r.y += o.y; r.z += o.z; r.w += o.w;
                red4[s * 32 + c] = r;
            }
            __syncthreads();
        }
        if (s == 0) {
            float4 r = red4[c];
            float* outp = partial + ((size_t)b * QQ + q) * DD + 4 * c;
            outp[0] = r.x; outp[1] = r.y; outp[2] = r.z; outp[3] = r.w;
        }
    }
    // ---- P1b: compact own quarter's unmasked rows into LDS ----
    {
        int w = tid >> 6, lane = tid & 63;
        bool un = (tid < RQ) && !get_mask(mask, s_flag, (size_t)b * NN + n0 + tid);
        unsigned long long bal = __ballot(un);
        if (lane == 0) wbase[w] = __popcll(bal);
        __syncthreads();
        int base = 0;
        for (int ww = 0; ww < w; ++ww) base += wbase[ww];
        int off = __popcll(bal & ((1ULL << lane) - 1ULL));
        if (un) cidxL[base + off] = (unsigned short)tid;
        if (tid == 0) s_cnt = wbase[0] + wbase[1] + wbase[2] + wbase[3];
    }
    __syncthreads();
    if (tid == 0) sy_arrive(&sy[SY_CNTA]);

    // ---- P2: q0 computes query + qk for its b; siblings wait on flag ----
    if (q == 0) {
        if (tid == 0) sy_wait(&sy[SY_CNTA], QQ);
        __syncthreads();
        float* ge = poolf;            // 128
        float* sc = poolf + 128;      // 256
        float* qv = poolf + 384;      // 128
        float* qp = poolf + 512;      // 256
        if (tid < DD) {
            float g = 0.f;
            #pragma unroll
            for (int qq = 0; qq < QQ; ++qq) g += partial[((size_t)b * QQ + qq) * DD + tid];
            ge[tid] = g * (1.0f / NN);
        }
        {
            int src = (tid < DD) ? first[b] : prev[b];
            sc[tid] = X[xoff + (size_t)src * DD + (tid & 127)];
        }
        __syncthreads();
        int p = tid >> 7, d = tid & 127;
        {
            float a = 0.f;
            #pragma unroll 4
            for (int k = p * 64; k < p * 64 + 64; ++k)      a += ge[k] * Wfix[(size_t)k * DD + d];
            #pragma unroll 4
            for (int k = p * 128; k < p * 128 + 128; ++k)   a += sc[k] * Wstep[(size_t)k * DD + d];
            qp[p * DD + d] = a;
        }
        __syncthreads();
        if (tid < DD) qv[tid] = qp[tid] + qp[DD + tid];
        __syncthreads();
        {
            const float* wrow = Wnode + (size_t)d * 384;
            #pragma unroll
            for (int h = p * 4; h < p * 4 + 4; ++h) {
                const float4* wr = (const float4*)(wrow + h * 16);
                float a = 0.f;
                #pragma unroll
                for (int j4 = 0; j4 < 4; ++j4) {
                    float4 w = wr[j4];
                    a += w.x * qv[h * 16 + 4 * j4]     + w.y * qv[h * 16 + 4 * j4 + 1]
                       + w.z * qv[h * 16 + 4 * j4 + 2] + w.w * qv[h * 16 + 4 * j4 + 3];
                }
                qkg[((size_t)b * HH + h) * DD + d] = 0.25f * a;   // 1/sqrt(16)
            }
        }
        __syncthreads();
        if (tid == 0) sy_set(&sy[SY_QK]);
    }
    if (tid == 0) sy_wait(&sy[SY_QK], 1);
    __syncthreads();
    for (int i = tid; i < HH * DD; i += 256)
        qks[i >> 7][i & 127] = qkg[(size_t)b * HH * DD + i];
    __syncthreads();

    // ---- P3: fused compat -> exp(no-max, clamp 80) -> PV over compacted rows ----
    {
        float* redpv = poolf;                              // [4][8][128]
        const int g = tid & 15, r = tid >> 4, w = tid >> 6;
        int len = s_cnt;
        int iters = (len + 15) >> 4;
        float acc[HH][8];
        #pragma unroll
        for (int h = 0; h < HH; ++h)
            #pragma unroll
            for (int j = 0; j < 8; ++j) acc[h][j] = 0.f;
        float S[HH] = {0.f, 0.f, 0.f, 0.f, 0.f, 0.f, 0.f, 0.f};

        for (int it = 0; it < iters; ++it) {
            int k = it * 16 + r;
            if (k < len) {
                int n = n0 + cidxL[k];
                const float4* xr = (const float4*)(X + xoff + (size_t)n * DD + 8 * g);
                float4 v0 = xr[0], v1 = xr[1];
                float v[8] = {v0.x, v0.y, v0.z, v0.w, v1.x, v1.y, v1.z, v1.w};
                float cp[HH];
                #pragma unroll
                for (int h = 0; h < HH; ++h) {
                    const float4* qr = (const float4*)&qks[h][8 * g];
                    float4 q0 = qr[0], q1 = qr[1];
                    cp[h] = v[0] * q0.x + v[1] * q0.y + v[2] * q0.z + v[3] * q0.w
                          + v[4] * q1.x + v[5] * q1.y + v[6] * q1.z + v[7] * q1.w;
                }
                #pragma unroll
                for (int h = 0; h < HH; ++h) {
                    cp[h] += __shfl_xor(cp[h], 1, 16);
                    cp[h] += __shfl_xor(cp[h], 2, 16);
                    cp[h] += __shfl_xor(cp[h], 4, 16);
                    cp[h] += __shfl_xor(cp[h], 8, 16);
                }
                #pragma unroll
                for (int h = 0; h < HH; ++h) {
                    float pe = __expf(fminf(cp[h], 80.f));
                    S[h] += pe;
                    #pragma unroll
                    for (int j = 0; j < 8; ++j) acc[h][j] += pe * v[j];
                }
            }
        }
        #pragma unroll
        for (int h = 0; h < HH; ++h) {
            S[h] += __shfl_xor(S[h], 16, 64);
            S[h] += __shfl_xor(S[h], 32, 64);
            #pragma unroll
            for (int j = 0; j < 8; ++j) {
                acc[h][j] += __shfl_xor(acc[h][j], 16, 64);
                acc[h][j] += __shfl_xor(acc[h][j], 32, 64);
            }
        }
        if ((tid & 63) < 16) {
            #pragma unroll
            for (int h = 0; h < HH; ++h) {
                *((float4*)&redpv[((size_t)w * HH + h) * DD + 8 * g]) =
                    make_float4(acc[h][0], acc[h][1], acc[h][2], acc[h][3]);
                *((float4*)&redpv[((size_t)w * HH + h) * DD + 8 * g + 4]) =
                    make_float4(acc[h][4], acc[h][5], acc[h][6], acc[h][7]);
            }
            if (g == 0) {
                #pragma unroll
                for (int h = 0; h < HH; ++h) redS[w][h] = S[h];
            }
        }
        __syncthreads();
        for (int idx = tid; idx < HH * DD; idx += 256) {
            int h = idx >> 7, d = idx & 127;
            pvp[(((size_t)b * QQ + q) * HH + h) * DD + d] =
                redpv[(0 * HH + h) * DD + d] + redpv[(1 * HH + h) * DD + d] +
                redpv[(2 * HH + h) * DD + d] + redpv[(3 * HH + h) * DD + d];
        }
        if (tid < HH)
            sqw[((size_t)b * QQ + q) * HH + tid] =
                redS[0][tid] + redS[1][tid] + redS[2][tid] + redS[3][tid];
    }
    __syncthreads();
    if (tid == 0) sy_arrive(&sy[SY_CNTC]);

    // ---- P4: q0 combines PV -> heads -> glimpse -> gq; siblings wait ----
    if (q == 0) {
        if (tid == 0) sy_wait(&sy[SY_CNTC], QQ);
        __syncthreads();
        float* xa = poolf;            // 1024
        float* hd = poolf + 1024;     // 128
        float* gl = poolf + 1152;     // 128
        float* qp = poolf + 1280;     // 256
        if (tid < HH) {
            float S = 0.f;
            #pragma unroll
            for (int qq = 0; qq < QQ; ++qq) S += sqw[((size_t)b * QQ + qq) * HH + tid];
            Sh[tid] = 1.0f / S;
        }
        __syncthreads();
        for (int idx = tid; idx < HH * DD; idx += 256) {
            int h = idx >> 7, d = idx & 127;
            float a = 0.f;
            #pragma unroll
            for (int qq = 0; qq < QQ; ++qq)
                a += pvp[(((size_t)b * QQ + qq) * HH + h) * DD + d];
            xa[h * DD + d] = a * Sh[h];
        }
        __syncthreads();
        int p = tid >> 7, t = tid & 127;
        {
            int h = t >> 4;
            float a = 0.f;
            #pragma unroll 4
            for (int d = p * 64; d < p * 64 + 64; ++d)
                a += xa[h * DD + d] * Wnode[(size_t)d * 384 + 128 + t];
            qp[p * DD + t] = a;
        }
        __syncthreads();
        if (tid < DD) hd[tid] = qp[tid] + qp[DD + tid];
        __syncthreads();
        {
            float a = 0.f;
            #pragma unroll 4
            for (int k = p * 64; k < p * 64 + 64; ++k) a += hd[k] * Wout[(size_t)k * DD + t];
            qp[p * DD + t] = a;
        }
        __syncthreads();
        if (tid < DD) gl[tid] = qp[tid] + qp[DD + tid];
        __syncthreads();
        {
            const float4* wr = (const float4*)(Wnode + (size_t)t * 384 + 256 + p * 64);
            float a = 0.f;
            #pragma unroll
            for (int j4 = 0; j4 < 16; ++j4) {
                float4 w = wr[j4];
                int k = p * 64 + 4 * j4;
                a += w.x * gl[k] + w.y * gl[k + 1] + w.z * gl[k + 2] + w.w * gl[k + 3];
            }
            qp[p * DD + t] = a;
        }
        __syncthreads();
        if (tid < DD)
            gqg[(size_t)b * DD + tid] = (qp[tid] + qp[DD + tid]) * 0.08838834764831845f;
        __syncthreads();
        if (tid == 0) sy_set(&sy[SY_GQ]);
    }
    if (tid == 0) sy_wait(&sy[SY_GQ], 1);
    __syncthreads();
    if (tid < DD) gqv[tid] = gqg[(size_t)b * DD + tid];
    if (tid < RQ) lgl[tid] = NEG;
    __syncthreads();

    // ---- P5: logits over compacted rows, exp-partials at fixed base 10 ----
    {
        int len = s_cnt;
        int g = tid & 7, rr = tid >> 3;
        int iters = (len + 31) >> 5;
        float esum = 0.f;
        for (int it = 0; it < iters; ++it) {
            int k = it * 32 + rr;
            if (k < len) {
                int nl = cidxL[k];
                const float4* xr = (const float4*)(X + xoff + (size_t)(n0 + nl) * DD);
                float a = 0.f;
                #pragma unroll
                for (int i = 0; i < 4; ++i) {
                    float4 v = xr[g + 8 * i];
                    int col = 4 * (g + 8 * i);
                    a += v.x * gqv[col] + v.y * gqv[col + 1]
                       + v.z * gqv[col + 2] + v.w * gqv[col + 3];
                }
                a += __shfl_xor(a, 1, 8);
                a += __shfl_xor(a, 2, 8);
                a += __shfl_xor(a, 4, 8);
                if (g == 0) {
                    float l = 10.0f * tanhf(a);
                    lgl[nl] = l;
                    esum += __expf(l - 10.0f);     // logits <= 10 always
                }
            }
        }
        #pragma unroll
        for (int off = 32; off >= 1; off >>= 1) esum += __shfl_xor(esum, off, 64);
        if ((tid & 63) == 0) redw[tid >> 6] = esum;
        __syncthreads();
        if (tid == 0) esumg[(size_t)b * QQ + q] = redw[0] + redw[1] + redw[2] + redw[3];
    }
    __syncthreads();
    if (tid == 0) { sy_arrive(&sy[SY_CNTE]); sy_wait(&sy[SY_CNTE], QQ); }
    __syncthreads();

    // ---- P6: lse + store own quarter ----
    {
        float s = esumg[(size_t)b * QQ] + esumg[(size_t)b * QQ + 1]
                + esumg[(size_t)b * QQ + 2] + esumg[(size_t)b * QQ + 3];
        float lse = 10.0f + logf(s);
        if (tid < RQ) out[(size_t)b * NN + n0 + tid] = lgl[tid] - lse;
    }
}

// ===========================================================================
// Fallback: proven mega-kernel (fp32), needs no workspace. (round 3/10: 108 us)
// ===========================================================================
__global__ __launch_bounds__(1024) void k_mega(
        const float* __restrict__ X, const float* __restrict__ Wnode,
        const float* __restrict__ Wfix, const float* __restrict__ Wstep,
        const float* __restrict__ Wout, const int* __restrict__ prev,
        const int* __restrict__ first, const void* __restrict__ mask,
        float* __restrict__ out) {
    int b = blockIdx.x, tid = threadIdx.x;
    __shared__ __align__(16) float cm[HH * 1024];
    __shared__ __align__(16) float qkl[HH * DD];
    __shared__ __align__(16) float qpart[8 * DD];
    __shared__ float xa[HH * DD];
    __shared__ float ge[DD], q[DD], sc[2 * DD], hd[DD], gl[DD], gqv[DD];
    __shared__ float red[16], invh[8];
    __shared__ int s_flag;
    const size_t xoff = (size_t)b * NN * DD;

    if (tid < 64) {
        const unsigned int* mw = (const unsigned int*)mask;
        unsigned int a0 = mw[tid], a1 = mw[tid + 64], a2 = mw[tid + 128], a3 = mw[tid + 192];
        int ii = (a0 <= 1u) && (a1 <= 1u) && (a2 <= 1u) && (a3 <= 1u);
        int ff = (a0 == 0u || a0 == 0x3F800000u) && (a1 == 0u || a1 == 0x3F800000u) &&
                 (a2 == 0u || a2 == 0x3F800000u) && (a3 == 0u || a3 == 0x3F800000u);
        int ai = __all(ii), af = __all(ff);
        if (tid == 0) s_flag = ai ? 1 : (af ? 2 : 0);
    }
    if (tid >= 256 && tid < 512) {
        int t = tid - 256;
        int src = (t < DD) ? first[b] : prev[b];
        sc[t] = X[xoff + (size_t)src * DD + (t & 127)];
    }
    {
        float4* red4 = (float4*)cm;
        int c = tid & 31, s = tid >> 5;
        const float4* Xr = (const float4*)(X + xoff);
        float4 acc = make_float4(0.f, 0.f, 0.f, 0.f);
        for (int n = s; n < NN; n += 32) {
            float4 v = Xr[n * 32 + c];
            acc.x += v.x; acc.y += v.y; acc.z += v.z; acc.w += v.w;
        }
        red4[s * 32 + c] = acc;
        __syncthreads();
        for (int st = 16; st >= 1; st >>= 1) {
            if (s < st) {
                float4 o = red4[(s + st) * 32 + c];
                float4 r = red4[s * 32 + c];
                r.x += o.x; r.y += o.y; r.z += o.z; r.w += o.w;
                red4[s * 32 + c] = r;
            }
            __syncthreads();
        }
        if (s == 0) {
            float4 r = red4[c];
            ge[4 * c] = r.x * (1.0f / NN); ge[4 * c + 1] = r.y * (1.0f / NN);
            ge[4 * c + 2] = r.z * (1.0f / NN); ge[4 * c + 3] = r.w * (1.0f / NN);
        }
        __syncthreads();
    }
    const int flag = s_flag;
    {
        int p = tid >> 7, d = tid & 127;
        float a = 0.f;
        for (int k = p * 16; k < p * 16 + 16; ++k) a += ge[k] * Wfix[k * DD + d];
        for (int k = p * 32; k < p * 32 + 32; ++k) a += sc[k] * Wstep[k * DD + d];
        qpart[p * DD + d] = a;
        __syncthreads();
        if (tid < DD) {
            float s = 0.f;
            for (int pp = 0; pp < 8; ++pp) s += qpart[pp * DD + tid];
            q[tid] = s;
        }
        __syncthreads();
        int d2 = tid >> 3, h = tid & 7;
        const float4* wr = (const float4*)(Wnode + (size_t)d2 * 384 + h * 16);
        float a2 = 0.f;
        for (int j4 = 0; j4 < 4; ++j4) {
            float4 w = wr[j4];
            a2 += w.x * q[h * 16 + 4 * j4]     + w.y * q[h * 16 + 4 * j4 + 1]
                + w.z * q[h * 16 + 4 * j4 + 2] + w.w * q[h * 16 + 4 * j4 + 3];
        }
        qkl[h * DD + d2] = 0.25f * a2;
        __syncthreads();
    }
    {
        int g = tid & 7;
        for (int it = 0; it < 8; ++it) {
            int n = it * 128 + (tid >> 3);
            if (n < NN) {
                float acc[HH] = {0.f, 0.f, 0.f, 0.f, 0.f, 0.f, 0.f, 0.f};
                const float4* xr = (const float4*)(X + xoff + (size_t)n * DD);
                for (int i = 0; i < 4; ++i) {
                    float4 v = xr[g + 8 * i];
                    int col = 4 * (g + 8 * i);
                    for (int h = 0; h < HH; ++h)
                        acc[h] += v.x * qkl[h * DD + col]     + v.y * qkl[h * DD + col + 1]
                                + v.z * qkl[h * DD + col + 2] + v.w * qkl[h * DD + col + 3];
                }
                for (int h = 0; h < HH; ++h) {
                    acc[h] += __shfl_xor(acc[h], 1, 8);
                    acc[h] += __shfl_xor(acc[h], 2, 8);
                    acc[h] += __shfl_xor(acc[h], 4, 8);
                }
                float val = acc[0];
                for (int h = 1; h < HH; ++h) val = (g == h) ? acc[h] : val;
                bool mk = get_mask(mask, flag, (size_t)b * NN + n);
                cm[g * 1024 + n] = mk ? NEG : val;
            }
        }
        __syncthreads();
    }
    {
        int h = tid >> 7, lane = tid & 127;
        float mx = -INFINITY;
        for (int n = lane; n < NN; n += 128) mx = fmaxf(mx, cm[h * 1024 + n]);
        for (int off = 32; off >= 1; off >>= 1) mx = fmaxf(mx, __shfl_xor(mx, off, 64));
        if ((tid & 63) == 0) red[tid >> 6] = mx;
        __syncthreads();
        float m_h = fmaxf(red[2 * h], red[2 * h + 1]);
        float sm = 0.f;
        for (int n = lane; n < NN; n += 128) {
            float p = __expf(cm[h * 1024 + n] - m_h);
            cm[h * 1024 + n] = p;
            sm += p;
        }
        for (int off = 32; off >= 1; off >>= 1) sm += __shfl_xor(sm, off, 64);
        __syncthreads();
        if ((tid & 63) == 0) red[tid >> 6] = sm;
        __syncthreads();
        if (tid < HH) invh[tid] = 1.0f / (red[2 * tid] + red[2 * tid + 1]);
        __syncthreads();
    }
    {
        int s = tid >> 7, d = tid & 127;
        float acc[HH] = {0.f, 0.f, 0.f, 0.f, 0.f, 0.f, 0.f, 0.f};
        for (int n = s; n < NN; n += 8) {
            float x = X[xoff + (size_t)n * DD + d];
            for (int h = 0; h < HH; ++h) acc[h] += cm[h * 1024 + n] * x;
        }
        __syncthreads();
        float* xp = cm;
        for (int h = 0; h < HH; ++h) xp[(s * HH + h) * DD + d] = acc[h];
        __syncthreads();
        if (s == 0) {
            for (int h = 0; h < HH; ++h) {
                float t = 0.f;
                for (int ss = 0; ss < 8; ++ss) t += xp[(ss * HH + h) * DD + d];
                xa[h * DD + d] = t * invh[h];
            }
        }
        __syncthreads();
    }
    {
        int p = tid >> 7, t = tid & 127;
        int h = t >> 4;
        float a = 0.f;
        for (int d = p * 16; d < p * 16 + 16; ++d)
            a += xa[h * DD + d] * Wnode[(size_t)d * 384 + 128 + t];
        qpart[p * DD + t] = a;
        __syncthreads();
        if (tid < DD) {
            float s = 0.f;
            for (int pp = 0; pp < 8; ++pp) s += qpart[pp * DD + tid];
            hd[tid] = s;
        }
        __syncthreads();
        a = 0.f;
        for (int k = p * 16; k < p * 16 + 16; ++k) a += hd[k] * Wout[(size_t)k * DD + t];
        qpart[p * DD + t] = a;
        __syncthreads();
        if (tid < DD) {
            float s = 0.f;
            for (int pp = 0; pp < 8; ++pp) s += qpart[pp * DD + tid];
            gl[tid] = s;
        }
        __syncthreads();
        const float4* wr = (const float4*)(Wnode + (size_t)t * 384 + 256 + p * 16);
        a = 0.f;
        for (int j4 = 0; j4 < 4; ++j4) {
            float4 w = wr[j4];
            int k = p * 16 + 4 * j4;
            a += w.x * gl[k] + w.y * gl[k + 1] + w.z * gl[k + 2] + w.w * gl[k + 3];
        }
        qpart[p * DD + t] = a;
        __syncthreads();
        if (tid < DD) {
            float s = 0.f;
            for (int pp = 0; pp < 8; ++pp) s += qpart[pp * DD + tid];
            gqv[tid] = s * 0.08838834764831845f;
        }
        __syncthreads();
    }
    {
        float* lg = qkl;
        int g = tid & 7;
        for (int it = 0; it < 8; ++it) {
            int n = it * 128 + (tid >> 3);
            if (n < NN) {
                const float4* xr = (const float4*)(X + xoff + (size_t)n * DD);
                float a = 0.f;
                for (int i = 0; i < 4; ++i) {
                    float4 v = xr[g + 8 * i];
                    int col = 4 * (g + 8 * i);
                    a += v.x * gqv[col] + v.y * gqv[col + 1] + v.z * gqv[col + 2] + v.w * gqv[col + 3];
                }
                a += __shfl_xor(a, 1, 8);
                a += __shfl_xor(a, 2, 8);
                a += __shfl_xor(a, 4, 8);
                if (g == 0) {
                    float lgt = 10.0f * tanhf(a);
                    lg[n] = get_mask(mask, flag, (size_t)b * NN + n) ? NEG : lgt;
                }
            }
        }
        __syncthreads();
        float v = (tid < NN) ? lg[tid] : -INFINITY;
        float mx = v;
        for (int off = 32; off >= 1; off >>= 1) mx = fmaxf(mx, __shfl_xor(mx, off, 64));
        if ((tid & 63) == 0) red[tid >> 6] = mx;
        __syncthreads();
        float m = red[0];
        for (int w = 1; w < 16; ++w) m = fmaxf(m, red[w]);
        float e = (tid < NN) ? __expf(v - m) : 0.f;
        float sm = e;
        for (int off = 32; off >= 1; off >>= 1) sm += __shfl_xor(sm, off, 64);
        __syncthreads();
        if ((tid & 63) == 0) red[tid >> 6] = sm;
        __syncthreads();
        float s2 = 0.f;
        for (int w = 0; w < 16; ++w) s2 += red[w];
        float lse = m + logf(s2);
        if (tid < NN) out[(size_t)b * NN + tid] = v - lse;
    }
}

// ---------------------------------------------------------------------------
extern "C" void kernel_launch(void* const* d_in, const int* in_sizes, int n_in,
                              void* d_out, int out_size, void* d_ws, size_t ws_size,
                              hipStream_t stream) {
    const float* X     = (const float*)d_in[0];
    const float* Wnode = (const float*)d_in[1];
    const float* Wfix  = (const float*)d_in[2];
    const float* Wstep = (const float*)d_in[3];
    const float* Wout  = (const float*)d_in[4];
    const int*   prev  = (const int*)d_in[5];
    const int*   first = (const int*)d_in[6];
    const void*  mask  = d_in[7];
    float* out = (float*)d_out;

    char* wsb = (char*)d_ws;
    int*   syg     = (int*)wsb;                              // 256*16 ints = 16 KB
    float* partial = (float*)(wsb + 16384);                  // B*Q*D   = 131072 f
    float* qkg     = partial + (size_t)BB * QQ * DD;         // B*H*D   = 262144 f
    float* sqw     = qkg + (size_t)BB * HH * DD;             // B*Q*H   = 8192 f
    float* pvp     = sqw + (size_t)BB * QQ * HH;             // B*Q*H*D = 1048576 f
    float* gqg     = pvp + (size_t)BB * QQ * HH * DD;        // B*D     = 32768 f
    float* esumg   = gqg + (size_t)BB * DD;                  // B*Q     = 1024 f
    const size_t need = 16384 + sizeof(float) * (
        (size_t)BB * QQ * DD + (size_t)BB * HH * DD + (size_t)BB * QQ * HH +
        (size_t)BB * QQ * HH * DD + (size_t)BB * DD + (size_t)BB * QQ);

    int maxb = 0;
    bool ok = (ws_size >= need) &&
              (hipOccupancyMaxActiveBlocksPerMultiprocessor(&maxb, (const void*)k_one,
                                                            256, 0) == hipSuccess) &&
              (maxb >= QQ);
    if (ok) {
        // counters MUST be zero at kernel start on every call (replay-safe)
        hipMemsetAsync(syg, 0, 16384, stream);
        k_one<<<BB * QQ, 256, 0, stream>>>(X, Wnode, Wfix, Wstep, Wout, prev, first,
                                           mask, syg, partial, qkg, sqw, pvp, gqg,
                                           esumg, out);
    } else {
        k_mega<<<BB, 1024, 0, stream>>>(X, Wnode, Wfix, Wstep, Wout,
                                        prev, first, mask, out);
    }
}

// Round 15
// 107.175 us; speedup vs baseline: 1.2258x; 1.0028x over previous
//
#include <hip/hip_runtime.h>
#include <math.h>

#define BB 256
#define NN 1000
#define DD 128
#define HH 8
#define QQ 4            // sibling blocks per batch element
#define RQ 250          // rows per quarter
#define NEG -1e9f

#define SY_CNTA 0
#define SY_CNTC 1
#define SY_CNTE 2

__device__ __forceinline__ bool get_mask(const void* m, int flag, size_t idx) {
    if (flag == 1) return ((const int*)m)[idx] != 0;
    if (flag == 2) return ((const float*)m)[idx] != 0.0f;
    return ((const unsigned char*)m)[idx] != 0;
}

__device__ __forceinline__ void sy_barrier(int* p, int tid, int tgt) {
    if (tid == 0) {
        __builtin_amdgcn_fence(__ATOMIC_RELEASE, "agent");
        __hip_atomic_fetch_add(p, 1, __ATOMIC_RELAXED, __HIP_MEMORY_SCOPE_AGENT);
        while (__hip_atomic_load(p, __ATOMIC_RELAXED, __HIP_MEMORY_SCOPE_AGENT) < tgt)
            __builtin_amdgcn_s_sleep(8);
        __builtin_amdgcn_fence(__ATOMIC_ACQUIRE, "agent");
    }
    __syncthreads();
}

// ===========================================================================
// Single fused kernel: grid BB*QQ = 1024 blocks (b,q), 256 thr, 4 blocks/CU.
// No q0-only phases: siblings redundantly compute qk and gq (weights L2-hit).
// 3 per-b counter barriers. P3 uses 32-lane rows + acc[8][4] (no VGPR spill).
// ===========================================================================
__global__ __launch_bounds__(256, 4) void k_one(
        const float* __restrict__ X, const float* __restrict__ Wnode,
        const float* __restrict__ Wfix, const float* __restrict__ Wstep,
        const float* __restrict__ Wout, const int* __restrict__ prev,
        const int* __restrict__ first, const void* __restrict__ mask,
        int* __restrict__ syg, float* __restrict__ partial,
        float* __restrict__ sqw, float* __restrict__ pvp,
        float* __restrict__ esumg, float* __restrict__ out) {
    const int bid = blockIdx.x, tid = threadIdx.x;
    const int b = bid >> 2, q = bid & 3;
    const int n0 = q * RQ;
    const size_t xoff = (size_t)b * NN * DD;
    int* sy = syg + b * 16;

    __shared__ __align__(16) float pool[4096];      // 16 KB phase-overlaid
    __shared__ __align__(16) float qks[HH][DD];     // 4 KB  (P2 -> P3)
    __shared__ float gqv[DD];                       // P4 -> P5
    __shared__ float lgl[256];                      // P5 -> P6
    __shared__ unsigned short cidxL[256];
    __shared__ float redS[4][HH];
    __shared__ float Sh[HH];
    __shared__ float redw[4];
    __shared__ int wbase[4];
    __shared__ int s_flag, s_cnt;

    // ---- P0: mask dtype detect (local, cheap) ----
    if (tid < 64) {
        const unsigned int* mw = (const unsigned int*)mask;
        unsigned int a0 = mw[tid], a1 = mw[tid + 64], a2 = mw[tid + 128], a3 = mw[tid + 192];
        int ii = (a0 <= 1u) && (a1 <= 1u) && (a2 <= 1u) && (a3 <= 1u);
        int ff = (a0 == 0u || a0 == 0x3F800000u) && (a1 == 0u || a1 == 0x3F800000u) &&
                 (a2 == 0u || a2 == 0x3F800000u) && (a3 == 0u || a3 == 0x3F800000u);
        int ai = __all(ii), af = __all(ff);
        if (tid == 0) s_flag = ai ? 1 : (af ? 2 : 0);
    }

    // ---- P1a: mean partial over own quarter (the one HBM pass over X) ----
    {
        float4* red4 = (float4*)pool;               // [8][32]
        int c = tid & 31, s = tid >> 5;
        const float4* Xr = (const float4*)(X + xoff);
        float4 acc = make_float4(0.f, 0.f, 0.f, 0.f);
        for (int nl = s; nl < RQ; nl += 8) {
            float4 v = Xr[(n0 + nl) * 32 + c];
            acc.x += v.x; acc.y += v.y; acc.z += v.z; acc.w += v.w;
        }
        red4[s * 32 + c] = acc;
        __syncthreads();
        for (int st = 4; st >= 1; st >>= 1) {
            if (s < st) {
                float4 o = red4[(s + st) * 32 + c];
                float4 r = red4[s * 32 + c];
                r.x += o.x; r.y += o.y; r.z += o.z; r.w += o.w;
                red4[s * 32 + c] = r;
            }
            __syncthreads();
        }
        if (s == 0) {
            float4 r = red4[c];
            float* outp = partial + ((size_t)b * QQ + q) * DD + 4 * c;
            outp[0] = r.x; outp[1] = r.y; outp[2] = r.z; outp[3] = r.w;
        }
    }
    // ---- P1b: compact own quarter's unmasked rows into LDS ----
    {
        int w = tid >> 6, lane = tid & 63;
        bool un = (tid < RQ) && !get_mask(mask, s_flag, (size_t)b * NN + n0 + tid);
        unsigned long long bal = __ballot(un);
        if (lane == 0) wbase[w] = __popcll(bal);
        __syncthreads();
        int base = 0;
        for (int ww = 0; ww < w; ++ww) base += wbase[ww];
        int off = __popcll(bal & ((1ULL << lane) - 1ULL));
        if (un) cidxL[base + off] = (unsigned short)tid;
        if (tid == 0) s_cnt = wbase[0] + wbase[1] + wbase[2] + wbase[3];
    }
    __syncthreads();
    sy_barrier(&sy[SY_CNTA], tid, QQ);

    // ---- P2 (ALL blocks, redundant): mean -> query -> qks[8][128] in LDS ----
    {
        float* ge = pool;            // 128
        float* sc = pool + 128;      // 256
        float* qv = pool + 384;      // 128
        float* qp = pool + 512;      // 256
        if (tid < DD) {
            float g = 0.f;
            #pragma unroll
            for (int qq = 0; qq < QQ; ++qq) g += partial[((size_t)b * QQ + qq) * DD + tid];
            ge[tid] = g * (1.0f / NN);
        }
        {
            int src = (tid < DD) ? first[b] : prev[b];
            sc[tid] = X[xoff + (size_t)src * DD + (tid & 127)];
        }
        __syncthreads();
        int p = tid >> 7, d = tid & 127;
        {
            float a = 0.f;
            #pragma unroll 8
            for (int k = p * 64; k < p * 64 + 64; ++k)      a += ge[k] * Wfix[(size_t)k * DD + d];
            #pragma unroll 8
            for (int k = p * 128; k < p * 128 + 128; ++k)   a += sc[k] * Wstep[(size_t)k * DD + d];
            qp[p * DD + d] = a;
        }
        __syncthreads();
        if (tid < DD) qv[tid] = qp[tid] + qp[DD + tid];
        __syncthreads();
        {
            const float* wrow = Wnode + (size_t)d * 384;
            #pragma unroll
            for (int h = p * 4; h < p * 4 + 4; ++h) {
                const float4* wr = (const float4*)(wrow + h * 16);
                float a = 0.f;
                #pragma unroll
                for (int j4 = 0; j4 < 4; ++j4) {
                    float4 w = wr[j4];
                    a += w.x * qv[h * 16 + 4 * j4]     + w.y * qv[h * 16 + 4 * j4 + 1]
                       + w.z * qv[h * 16 + 4 * j4 + 2] + w.w * qv[h * 16 + 4 * j4 + 3];
                }
                qks[h][d] = 0.25f * a;              // 1/sqrt(16)
            }
        }
        __syncthreads();
    }

    // ---- P3: compat -> exp(no-max, clamp 80) -> PV. 32 lanes/row, acc[8][4] ----
    {
        float* redpv = pool;                        // [4][8][128] = 16 KB
        const int g = tid & 31, r = tid >> 5, w = tid >> 6;
        const int len = s_cnt;
        const int iters = (len + 7) >> 3;
        float acc[HH][4];
        #pragma unroll
        for (int h = 0; h < HH; ++h) {
            acc[h][0] = 0.f; acc[h][1] = 0.f; acc[h][2] = 0.f; acc[h][3] = 0.f;
        }
        float S[HH] = {0.f, 0.f, 0.f, 0.f, 0.f, 0.f, 0.f, 0.f};

        for (int it = 0; it < iters; ++it) {
            int k = it * 8 + r;
            bool valid = (k < len);
            int kk = valid ? k : (len - 1);         // len>=1 when iters>0
            int n = n0 + cidxL[kk];
            float4 v = *(const float4*)(X + xoff + (size_t)n * DD + 4 * g);
            float cp[HH];
            #pragma unroll
            for (int h = 0; h < HH; ++h) {
                cp[h] = v.x * qks[h][4 * g]     + v.y * qks[h][4 * g + 1]
                      + v.z * qks[h][4 * g + 2] + v.w * qks[h][4 * g + 3];
            }
            #pragma unroll
            for (int h = 0; h < HH; ++h) {
                cp[h] += __shfl_xor(cp[h], 1, 32);
                cp[h] += __shfl_xor(cp[h], 2, 32);
                cp[h] += __shfl_xor(cp[h], 4, 32);
                cp[h] += __shfl_xor(cp[h], 8, 32);
                cp[h] += __shfl_xor(cp[h], 16, 32);
            }
            #pragma unroll
            for (int h = 0; h < HH; ++h) {
                float pe = valid ? __expf(fminf(cp[h], 80.f)) : 0.f;
                S[h] += pe;
                acc[h][0] += pe * v.x; acc[h][1] += pe * v.y;
                acc[h][2] += pe * v.z; acc[h][3] += pe * v.w;
            }
        }
        // cross-slot reduce within wave (slot 2w <-> 2w+1 via lane^32)
        #pragma unroll
        for (int h = 0; h < HH; ++h) {
            S[h] += __shfl_xor(S[h], 32, 64);
            acc[h][0] += __shfl_xor(acc[h][0], 32, 64);
            acc[h][1] += __shfl_xor(acc[h][1], 32, 64);
            acc[h][2] += __shfl_xor(acc[h][2], 32, 64);
            acc[h][3] += __shfl_xor(acc[h][3], 32, 64);
        }
        if ((tid & 63) < 32) {
            #pragma unroll
            for (int h = 0; h < HH; ++h)
                *((float4*)&redpv[((size_t)w * HH + h) * DD + 4 * g]) =
                    make_float4(acc[h][0], acc[h][1], acc[h][2], acc[h][3]);
            if (g == 0) {
                #pragma unroll
                for (int h = 0; h < HH; ++h) redS[w][h] = S[h];
            }
        }
        __syncthreads();
        for (int idx = tid; idx < HH * DD; idx += 256) {
            int h = idx >> 7, d = idx & 127;
            pvp[(((size_t)b * QQ + q) * HH + h) * DD + d] =
                redpv[(0 * HH + h) * DD + d] + redpv[(1 * HH + h) * DD + d] +
                redpv[(2 * HH + h) * DD + d] + redpv[(3 * HH + h) * DD + d];
        }
        if (tid < HH)
            sqw[((size_t)b * QQ + q) * HH + tid] =
                redS[0][tid] + redS[1][tid] + redS[2][tid] + redS[3][tid];
    }
    __syncthreads();
    sy_barrier(&sy[SY_CNTC], tid, QQ);

    // ---- P4 (ALL blocks, redundant): combine -> heads -> glimpse -> gq ----
    {
        float* xa = pool;            // 1024
        float* hd = pool + 1024;     // 128
        float* gl = pool + 1152;     // 128
        float* qp = pool + 1280;     // 256
        if (tid < HH) {
            float S = 0.f;
            #pragma unroll
            for (int qq = 0; qq < QQ; ++qq) S += sqw[((size_t)b * QQ + qq) * HH + tid];
            Sh[tid] = 1.0f / S;
        }
        if (tid < RQ) lgl[tid] = NEG;
        __syncthreads();
        for (int idx = tid; idx < HH * DD; idx += 256) {
            int h = idx >> 7, d = idx & 127;
            float a = 0.f;
            #pragma unroll
            for (int qq = 0; qq < QQ; ++qq)
                a += pvp[(((size_t)b * QQ + qq) * HH + h) * DD + d];
            xa[h * DD + d] = a * Sh[h];
        }
        __syncthreads();
        int p = tid >> 7, t = tid & 127;
        {
            int h = t >> 4;
            float a = 0.f;
            #pragma unroll 8
            for (int d = p * 64; d < p * 64 + 64; ++d)
                a += xa[h * DD + d] * Wnode[(size_t)d * 384 + 128 + t];
            qp[p * DD + t] = a;
        }
        __syncthreads();
        if (tid < DD) hd[tid] = qp[tid] + qp[DD + tid];
        __syncthreads();
        {
            float a = 0.f;
            #pragma unroll 8
            for (int k = p * 64; k < p * 64 + 64; ++k) a += hd[k] * Wout[(size_t)k * DD + t];
            qp[p * DD + t] = a;
        }
        __syncthreads();
        if (tid < DD) gl[tid] = qp[tid] + qp[DD + tid];
        __syncthreads();
        {
            const float4* wr = (const float4*)(Wnode + (size_t)t * 384 + 256 + p * 64);
            float a = 0.f;
            #pragma unroll
            for (int j4 = 0; j4 < 16; ++j4) {
                float4 w = wr[j4];
                int k = p * 64 + 4 * j4;
                a += w.x * gl[k] + w.y * gl[k + 1] + w.z * gl[k + 2] + w.w * gl[k + 3];
            }
            qp[p * DD + t] = a;
        }
        __syncthreads();
        if (tid < DD) gqv[tid] = (qp[tid] + qp[DD + tid]) * 0.08838834764831845f;
        __syncthreads();
    }

    // ---- P5: logits over compacted rows, exp-partials at fixed base 10 ----
    {
        const int len = s_cnt;
        const int iters = (len + 31) >> 5;
        int g = tid & 7, rr = tid >> 3;
        float esum = 0.f;
        for (int it = 0; it < iters; ++it) {
            int k = it * 32 + rr;
            bool valid = (k < len);
            int kk = valid ? k : (len - 1);
            int nl = cidxL[kk];
            const float4* xr = (const float4*)(X + xoff + (size_t)(n0 + nl) * DD);
            float a = 0.f;
            #pragma unroll
            for (int i = 0; i < 4; ++i) {
                float4 v = xr[g + 8 * i];
                int col = 4 * (g + 8 * i);
                a += v.x * gqv[col] + v.y * gqv[col + 1]
                   + v.z * gqv[col + 2] + v.w * gqv[col + 3];
            }
            a += __shfl_xor(a, 1, 8);
            a += __shfl_xor(a, 2, 8);
            a += __shfl_xor(a, 4, 8);
            if (g == 0 && valid) {
                float l = 10.0f * tanhf(a);
                lgl[nl] = l;
                esum += __expf(l - 10.0f);          // logits <= 10 always
            }
        }
        #pragma unroll
        for (int off = 32; off >= 1; off >>= 1) esum += __shfl_xor(esum, off, 64);
        if ((tid & 63) == 0) redw[tid >> 6] = esum;
        __syncthreads();
        if (tid == 0) esumg[(size_t)b * QQ + q] = redw[0] + redw[1] + redw[2] + redw[3];
    }
    __syncthreads();
    sy_barrier(&sy[SY_CNTE], tid, QQ);

    // ---- P6: lse + store own quarter ----
    {
        float s = esumg[(size_t)b * QQ] + esumg[(size_t)b * QQ + 1]
                + esumg[(size_t)b * QQ + 2] + esumg[(size_t)b * QQ + 3];
        float lse = 10.0f + logf(s);
        if (tid < RQ) out[(size_t)b * NN + n0 + tid] = lgl[tid] - lse;
    }
}

// ===========================================================================
// Fallback: proven mega-kernel (fp32), needs no workspace. (~108 us)
// ===========================================================================
__global__ __launch_bounds__(1024) void k_mega(
        const float* __restrict__ X, const float* __restrict__ Wnode,
        const float* __restrict__ Wfix, const float* __restrict__ Wstep,
        const float* __restrict__ Wout, const int* __restrict__ prev,
        const int* __restrict__ first, const void* __restrict__ mask,
        float* __restrict__ out) {
    int b = blockIdx.x, tid = threadIdx.x;
    __shared__ __align__(16) float cm[HH * 1024];
    __shared__ __align__(16) float qkl[HH * DD];
    __shared__ __align__(16) float qpart[8 * DD];
    __shared__ float xa[HH * DD];
    __shared__ float ge[DD], q[DD], sc[2 * DD], hd[DD], gl[DD], gqv[DD];
    __shared__ float red[16], invh[8];
    __shared__ int s_flag;
    const size_t xoff = (size_t)b * NN * DD;

    if (tid < 64) {
        const unsigned int* mw = (const unsigned int*)mask;
        unsigned int a0 = mw[tid], a1 = mw[tid + 64], a2 = mw[tid + 128], a3 = mw[tid + 192];
        int ii = (a0 <= 1u) && (a1 <= 1u) && (a2 <= 1u) && (a3 <= 1u);
        int ff = (a0 == 0u || a0 == 0x3F800000u) && (a1 == 0u || a1 == 0x3F800000u) &&
                 (a2 == 0u || a2 == 0x3F800000u) && (a3 == 0u || a3 == 0x3F800000u);
        int ai = __all(ii), af = __all(ff);
        if (tid == 0) s_flag = ai ? 1 : (af ? 2 : 0);
    }
    if (tid >= 256 && tid < 512) {
        int t = tid - 256;
        int src = (t < DD) ? first[b] : prev[b];
        sc[t] = X[xoff + (size_t)src * DD + (t & 127)];
    }
    {
        float4* red4 = (float4*)cm;
        int c = tid & 31, s = tid >> 5;
        const float4* Xr = (const float4*)(X + xoff);
        float4 acc = make_float4(0.f, 0.f, 0.f, 0.f);
        for (int n = s; n < NN; n += 32) {
            float4 v = Xr[n * 32 + c];
            acc.x += v.x; acc.y += v.y; acc.z += v.z; acc.w += v.w;
        }
        red4[s * 32 + c] = acc;
        __syncthreads();
        for (int st = 16; st >= 1; st >>= 1) {
            if (s < st) {
                float4 o = red4[(s + st) * 32 + c];
                float4 r = red4[s * 32 + c];
                r.x += o.x; r.y += o.y; r.z += o.z; r.w += o.w;
                red4[s * 32 + c] = r;
            }
            __syncthreads();
        }
        if (s == 0) {
            float4 r = red4[c];
            ge[4 * c] = r.x * (1.0f / NN); ge[4 * c + 1] = r.y * (1.0f / NN);
            ge[4 * c + 2] = r.z * (1.0f / NN); ge[4 * c + 3] = r.w * (1.0f / NN);
        }
        __syncthreads();
    }
    const int flag = s_flag;
    {
        int p = tid >> 7, d = tid & 127;
        float a = 0.f;
        for (int k = p * 16; k < p * 16 + 16; ++k) a += ge[k] * Wfix[k * DD + d];
        for (int k = p * 32; k < p * 32 + 32; ++k) a += sc[k] * Wstep[k * DD + d];
        qpart[p * DD + d] = a;
        __syncthreads();
        if (tid < DD) {
            float s = 0.f;
            for (int pp = 0; pp < 8; ++pp) s += qpart[pp * DD + tid];
            q[tid] = s;
        }
        __syncthreads();
        int d2 = tid >> 3, h = tid & 7;
        const float4* wr = (const float4*)(Wnode + (size_t)d2 * 384 + h * 16);
        float a2 = 0.f;
        for (int j4 = 0; j4 < 4; ++j4) {
            float4 w = wr[j4];
            a2 += w.x * q[h * 16 + 4 * j4]     + w.y * q[h * 16 + 4 * j4 + 1]
                + w.z * q[h * 16 + 4 * j4 + 2] + w.w * q[h * 16 + 4 * j4 + 3];
        }
        qkl[h * DD + d2] = 0.25f * a2;
        __syncthreads();
    }
    {
        int g = tid & 7;
        for (int it = 0; it < 8; ++it) {
            int n = it * 128 + (tid >> 3);
            if (n < NN) {
                float acc[HH] = {0.f, 0.f, 0.f, 0.f, 0.f, 0.f, 0.f, 0.f};
                const float4* xr = (const float4*)(X + xoff + (size_t)n * DD);
                for (int i = 0; i < 4; ++i) {
                    float4 v = xr[g + 8 * i];
                    int col = 4 * (g + 8 * i);
                    for (int h = 0; h < HH; ++h)
                        acc[h] += v.x * qkl[h * DD + col]     + v.y * qkl[h * DD + col + 1]
                                + v.z * qkl[h * DD + col + 2] + v.w * qkl[h * DD + col + 3];
                }
                for (int h = 0; h < HH; ++h) {
                    acc[h] += __shfl_xor(acc[h], 1, 8);
                    acc[h] += __shfl_xor(acc[h], 2, 8);
                    acc[h] += __shfl_xor(acc[h], 4, 8);
                }
                float val = acc[0];
                for (int h = 1; h < HH; ++h) val = (g == h) ? acc[h] : val;
                bool mk = get_mask(mask, flag, (size_t)b * NN + n);
                cm[g * 1024 + n] = mk ? NEG : val;
            }
        }
        __syncthreads();
    }
    {
        int h = tid >> 7, lane = tid & 127;
        float mx = -INFINITY;
        for (int n = lane; n < NN; n += 128) mx = fmaxf(mx, cm[h * 1024 + n]);
        for (int off = 32; off >= 1; off >>= 1) mx = fmaxf(mx, __shfl_xor(mx, off, 64));
        if ((tid & 63) == 0) red[tid >> 6] = mx;
        __syncthreads();
        float m_h = fmaxf(red[2 * h], red[2 * h + 1]);
        float sm = 0.f;
        for (int n = lane; n < NN; n += 128) {
            float p = __expf(cm[h * 1024 + n] - m_h);
            cm[h * 1024 + n] = p;
            sm += p;
        }
        for (int off = 32; off >= 1; off >>= 1) sm += __shfl_xor(sm, off, 64);
        __syncthreads();
        if ((tid & 63) == 0) red[tid >> 6] = sm;
        __syncthreads();
        if (tid < HH) invh[tid] = 1.0f / (red[2 * tid] + red[2 * tid + 1]);
        __syncthreads();
    }
    {
        int s = tid >> 7, d = tid & 127;
        float acc[HH] = {0.f, 0.f, 0.f, 0.f, 0.f, 0.f, 0.f, 0.f};
        for (int n = s; n < NN; n += 8) {
            float x = X[xoff + (size_t)n * DD + d];
            for (int h = 0; h < HH; ++h) acc[h] += cm[h * 1024 + n] * x;
        }
        __syncthreads();
        float* xp = cm;
        for (int h = 0; h < HH; ++h) xp[(s * HH + h) * DD + d] = acc[h];
        __syncthreads();
        if (s == 0) {
            for (int h = 0; h < HH; ++h) {
                float t = 0.f;
                for (int ss = 0; ss < 8; ++ss) t += xp[(ss * HH + h) * DD + d];
                xa[h * DD + d] = t * invh[h];
            }
        }
        __syncthreads();
    }
    {
        int p = tid >> 7, t = tid & 127;
        int h = t >> 4;
        float a = 0.f;
        for (int d = p * 16; d < p * 16 + 16; ++d)
            a += xa[h * DD + d] * Wnode[(size_t)d * 384 + 128 + t];
        qpart[p * DD + t] = a;
        __syncthreads();
        if (tid < DD) {
            float s = 0.f;
            for (int pp = 0; pp < 8; ++pp) s += qpart[pp * DD + tid];
            hd[tid] = s;
        }
        __syncthreads();
        a = 0.f;
        for (int k = p * 16; k < p * 16 + 16; ++k) a += hd[k] * Wout[(size_t)k * DD + t];
        qpart[p * DD + t] = a;
        __syncthreads();
        if (tid < DD) {
            float s = 0.f;
            for (int pp = 0; pp < 8; ++pp) s += qpart[pp * DD + tid];
            gl[tid] = s;
        }
        __syncthreads();
        const float4* wr = (const float4*)(Wnode + (size_t)t * 384 + 256 + p * 16);
        a = 0.f;
        for (int j4 = 0; j4 < 4; ++j4) {
            float4 w = wr[j4];
            int k = p * 16 + 4 * j4;
            a += w.x * gl[k] + w.y * gl[k + 1] + w.z * gl[k + 2] + w.w * gl[k + 3];
        }
        qpart[p * DD + t] = a;
        __syncthreads();
        if (tid < DD) {
            float s = 0.f;
            for (int pp = 0; pp < 8; ++pp) s += qpart[pp * DD + tid];
            gqv[tid] = s * 0.08838834764831845f;
        }
        __syncthreads();
    }
    {
        float* lg = qkl;
        int g = tid & 7;
        for (int it = 0; it < 8; ++it) {
            int n = it * 128 + (tid >> 3);
            if (n < NN) {
                const float4* xr = (const float4*)(X + xoff + (size_t)n * DD);
                float a = 0.f;
                for (int i = 0; i < 4; ++i) {
                    float4 v = xr[g + 8 * i];
                    int col = 4 * (g + 8 * i);
                    a += v.x * gqv[col] + v.y * gqv[col + 1] + v.z * gqv[col + 2] + v.w * gqv[col + 3];
                }
                a += __shfl_xor(a, 1, 8);
                a += __shfl_xor(a, 2, 8);
                a += __shfl_xor(a, 4, 8);
                if (g == 0) {
                    float lgt = 10.0f * tanhf(a);
                    lg[n] = get_mask(mask, flag, (size_t)b * NN + n) ? NEG : lgt;
                }
            }
        }
        __syncthreads();
        float v = (tid < NN) ? lg[tid] : -INFINITY;
        float mx = v;
        for (int off = 32; off >= 1; off >>= 1) mx = fmaxf(mx, __shfl_xor(mx, off, 64));
        if ((tid & 63) == 0) red[tid >> 6] = mx;
        __syncthreads();
        float m = red[0];
        for (int w = 1; w < 16; ++w) m = fmaxf(m, red[w]);
        float e = (tid < NN) ? __expf(v - m) : 0.f;
        float sm = e;
        for (int off = 32; off >= 1; off >>= 1) sm += __shfl_xor(sm, off, 64);
        __syncthreads();
        if ((tid & 63) == 0) red[tid >> 6] = sm;
        __syncthreads();
        float s2 = 0.f;
        for (int w = 0; w < 16; ++w) s2 += red[w];
        float lse = m + logf(s2);
        if (tid < NN) out[(size_t)b * NN + tid] = v - lse;
    }
}

// ---------------------------------------------------------------------------
extern "C" void kernel_launch(void* const* d_in, const int* in_sizes, int n_in,
                              void* d_out, int out_size, void* d_ws, size_t ws_size,
                              hipStream_t stream) {
    const float* X     = (const float*)d_in[0];
    const float* Wnode = (const float*)d_in[1];
    const float* Wfix  = (const float*)d_in[2];
    const float* Wstep = (const float*)d_in[3];
    const float* Wout  = (const float*)d_in[4];
    const int*   prev  = (const int*)d_in[5];
    const int*   first = (const int*)d_in[6];
    const void*  mask  = d_in[7];
    float* out = (float*)d_out;

    char* wsb = (char*)d_ws;
    int*   syg     = (int*)wsb;                              // 256*16 ints = 16 KB
    float* partial = (float*)(wsb + 16384);                  // B*Q*D   = 131072 f
    float* sqw     = partial + (size_t)BB * QQ * DD;         // B*Q*H   = 8192 f
    float* pvp     = sqw + (size_t)BB * QQ * HH;             // B*Q*H*D = 1048576 f
    float* esumg   = pvp + (size_t)BB * QQ * HH * DD;        // B*Q     = 1024 f
    const size_t need = 16384 + sizeof(float) * (
        (size_t)BB * QQ * DD + (size_t)BB * QQ * HH +
        (size_t)BB * QQ * HH * DD + (size_t)BB * QQ);

    int maxb = 0;
    bool ok = (ws_size >= need) &&
              (hipOccupancyMaxActiveBlocksPerMultiprocessor(&maxb, (const void*)k_one,
                                                            256, 0) == hipSuccess) &&
              (maxb >= QQ);
    if (ok) {
        hipMemsetAsync(syg, 0, 16384, stream);   // counters zero on every call
        k_one<<<BB * QQ, 256, 0, stream>>>(X, Wnode, Wfix, Wstep, Wout, prev, first,
                                           mask, syg, partial, sqw, pvp, esumg, out);
    } else {
        k_mega<<<BB, 1024, 0, stream>>>(X, Wnode, Wfix, Wstep, Wout,
                                        prev, first, mask, out);
    }
}